// Round 9
// baseline (424.995 us; speedup 1.0000x reference)
//
#include <hip/hip_runtime.h>
#include <math.h>

// GatedKalmaNet: B=1, L=1024, D=2048, HQ=16, HK=8, HD=128, CONV=4, CHUNK=64,
// Nc=16, NUM_ITER=30, RIDGE=0.02, EPS=1e-6.

#define LSEQ 1024
#define DM   2048
#define NHQ  16
#define NHK  8
#define HDIM 128
#define NCH  16
#define CSZ  64

typedef __attribute__((ext_vector_type(8))) short short8;
typedef __attribute__((ext_vector_type(4))) float floatx4;

// f32 -> bf16 RNE
__device__ __forceinline__ unsigned short f2bf(float f) {
  unsigned int u = __float_as_uint(f);
  u += 0x7fffu + ((u >> 16) & 1u);
  return (unsigned short)(u >> 16);
}
__device__ __forceinline__ float bf2f(unsigned short u) {
  return __uint_as_float(((unsigned int)u) << 16);
}

// packed f32x2 -> bf16x2 (RNE), lo half = first operand
__device__ __forceinline__ unsigned int cvtpk(float a, float b) {
  unsigned int r;
  asm("v_cvt_pk_bf16_f32 %0, %1, %2" : "=v"(r) : "v"(a), "v"(b));
  return r;
}

// async global->LDS, 16B per lane (wave-uniform LDS base + lane*16)
__device__ __forceinline__ void gload16(const unsigned short* g,
                                        unsigned short* l) {
  __builtin_amdgcn_global_load_lds(
      (const __attribute__((address_space(1))) unsigned int*)g,
      (__attribute__((address_space(3))) unsigned int*)l, 16, 0, 0);
}

// ---------------------------------------------------------------------------
// Fat transpose-cast: W[K][N] f32 -> Wt[N][K] bf16, one 128(k) x 64(n) tile.
// Valid tile ranges for 2048x2048: bk in [0,16), bn in [0,32).
// ---------------------------------------------------------------------------
__device__ __forceinline__ void tcast_fat(
    const float* __restrict__ W, unsigned short* __restrict__ Wt,
    int K, int N, int bn, int bk, int tid, float* __restrict__ t) {
  int k0 = bk * 128, n0 = bn * 64;
#pragma unroll
  for (int i = 0; i < 8; ++i) {
    int u = tid + i * 256;
    int r = u >> 4, c4 = u & 15;
    float4 v = *(const float4*)(W + (size_t)(k0 + r) * N + n0 + c4 * 4);
    float* dst = t + r * 65 + c4 * 4;
    dst[0] = v.x; dst[1] = v.y; dst[2] = v.z; dst[3] = v.w;
  }
  __syncthreads();
#pragma unroll
  for (int i = 0; i < 4; ++i) {
    int u2 = tid + i * 256;
    int klow = u2 & 7, nlow = (u2 >> 3) & 7;
    int khigh = (u2 >> 6) & 1, nhigh = (u2 >> 7) & 7;
    int k8 = (klow + khigh * 8) * 8;
    int nn = nlow + nhigh * 8;
    unsigned short o8[8];
#pragma unroll
    for (int j = 0; j < 8; ++j) o8[j] = f2bf(t[(k8 + j) * 65 + nn]);
    *(uint4*)(Wt + (size_t)(n0 + nn) * K + k0 + k8) = *(uint4*)o8;
  }
}

// ---------------------------------------------------------------------------
// prep: gates (0..255, 4 timesteps each) + tcast(Wq,Wk,Wv,Wg) (256..1791) +
// castbf(x) (1792..2303).
// ---------------------------------------------------------------------------
__global__ __launch_bounds__(256) void prep_kernel(
    const float* __restrict__ x, const float* __restrict__ Wq,
    const float* __restrict__ Wk, const float* __restrict__ Wv,
    const float* __restrict__ Wg, unsigned short* __restrict__ xb16,
    unsigned short* __restrict__ WtAll,
    const float* __restrict__ Wa, const float* __restrict__ Wbeta,
    const float* __restrict__ Wal, const float* __restrict__ A_log,
    const float* __restrict__ dtb, const float* __restrict__ bbv,
    const float* __restrict__ balv, float* __restrict__ glog,
    float* __restrict__ beta, float* __restrict__ alpha) {
  __shared__ float smem[128 * 65];
  int b = blockIdx.x, tid = threadIdx.x;
  if (b < 256) {
    // gates: 4 timesteps per block
    float* xr = smem;                       // 4 x 2048 floats = 32KB
    int ts0 = b * 4;
    for (int i = tid; i < 2048; i += 256)
      ((float4*)xr)[i] = ((const float4*)(x + (size_t)ts0 * 2048))[i];
    __syncthreads();
    int o = tid >> 4, p = tid & 15;
    if (o < 12) {
      const float* W = (o < 4) ? Wa : (o < 8) ? Wbeta : Wal;
      int h4 = (o & 3) * 4;
      float s[4][4];
#pragma unroll
      for (int t = 0; t < 4; ++t)
#pragma unroll
        for (int hh = 0; hh < 4; ++hh) s[t][hh] = 0.f;
      for (int j = 0; j < 32; ++j) {
        int k0 = j * 64 + p * 4;
        float4 w0 = *(const float4*)(W + (size_t)(k0 + 0) * 16 + h4);
        float4 w1 = *(const float4*)(W + (size_t)(k0 + 1) * 16 + h4);
        float4 w2 = *(const float4*)(W + (size_t)(k0 + 2) * 16 + h4);
        float4 w3 = *(const float4*)(W + (size_t)(k0 + 3) * 16 + h4);
#pragma unroll
        for (int t = 0; t < 4; ++t) {
          float4 xv = *(const float4*)(xr + t * 2048 + k0);
          s[t][0] = fmaf(xv.x, w0.x, s[t][0]);
          s[t][0] = fmaf(xv.y, w1.x, s[t][0]);
          s[t][0] = fmaf(xv.z, w2.x, s[t][0]);
          s[t][0] = fmaf(xv.w, w3.x, s[t][0]);
          s[t][1] = fmaf(xv.x, w0.y, s[t][1]);
          s[t][1] = fmaf(xv.y, w1.y, s[t][1]);
          s[t][1] = fmaf(xv.z, w2.y, s[t][1]);
          s[t][1] = fmaf(xv.w, w3.y, s[t][1]);
          s[t][2] = fmaf(xv.x, w0.z, s[t][2]);
          s[t][2] = fmaf(xv.y, w1.z, s[t][2]);
          s[t][2] = fmaf(xv.z, w2.z, s[t][2]);
          s[t][2] = fmaf(xv.w, w3.z, s[t][2]);
          s[t][3] = fmaf(xv.x, w0.w, s[t][3]);
          s[t][3] = fmaf(xv.y, w1.w, s[t][3]);
          s[t][3] = fmaf(xv.z, w2.w, s[t][3]);
          s[t][3] = fmaf(xv.w, w3.w, s[t][3]);
        }
      }
#pragma unroll
      for (int t = 0; t < 4; ++t)
#pragma unroll
        for (int hh = 0; hh < 4; ++hh) {
          float v = s[t][hh];
          v += __shfl_xor(v, 8);
          v += __shfl_xor(v, 4);
          v += __shfl_xor(v, 2);
          v += __shfl_xor(v, 1);
          s[t][hh] = v;
        }
      if (p == 0) {
        int m = o >> 2;
#pragma unroll
        for (int t = 0; t < 4; ++t) {
          int ts = ts0 + t;
#pragma unroll
          for (int hh = 0; hh < 4; ++hh) {
            int h = h4 + hh;
            float dot = s[t][hh];
            if (m == 0) {
              float za = dot + dtb[h];
              float sp = fmaxf(za, 0.f) + log1pf(expf(-fabsf(za)));
              glog[ts * 16 + h] = -expf(A_log[h]) * sp;
            } else if (m == 1) {
              beta[ts * 16 + h] = 1.f / (1.f + expf(-(dot + bbv[h])));
            } else {
              alpha[ts * 16 + h] = 1.f / (1.f + expf(-(dot + balv[h])));
            }
          }
        }
      }
    }
  } else if (b < 1792) {
    int r = b - 256;
    if (r < 512) {
      tcast_fat(Wq, WtAll, 2048, 2048, r & 31, r >> 5, tid, smem);
    } else if (r < 768) {
      int q = r - 512;
      tcast_fat(Wk, WtAll + (size_t)2048 * 2048, 2048, 1024, q & 15, q >> 4,
                tid, smem);
    } else if (r < 1024) {
      int q = r - 768;
      tcast_fat(Wv, WtAll + (size_t)3072 * 2048, 2048, 1024, q & 15, q >> 4,
                tid, smem);
    } else {
      int q = r - 1024;
      tcast_fat(Wg, WtAll + (size_t)4096 * 2048, 2048, 2048, q & 31, q >> 5,
                tid, smem);
    }
  } else {
    int i0 = (b - 1792) * 1024 + tid;
#pragma unroll
    for (int i = 0; i < 4; ++i) {
      int idx = i0 + i * 256;
      float4 v = ((const float4*)x)[idx];
      ushort4 u;
      u.x = f2bf(v.x); u.y = f2bf(v.y); u.z = f2bf(v.z); u.w = f2bf(v.w);
      ((ushort4*)xb16)[idx] = u;
    }
  }
}

// ---------------------------------------------------------------------------
// bf16 MFMA GEMM, m97 structure: C[M,N](f32) = A[M,K](bf16) @ Bt[N,K]^T.
// BM/BN template, BK=64.  256 thr = 4 waves (2x2 over BM/2 x BN/2).
// Round-9: gemm1 moved 128x64 -> 128x96 (grid 64x8 = 512 blocks = exactly
// 2/CU): makespan model rounds x 32steps x (a + b*BN) gives 96a+6144b for
// BN=64 vs 64a+6144b for BN=96 -- barrier/stage term a cut by 1/3, and
// 24 MFMAs per wave-step vs 16 against the same per-step stall.
// ---------------------------------------------------------------------------
template <int BM, int BN>
__global__ __launch_bounds__(256) void gemm_lds(
    const unsigned short* __restrict__ A, const unsigned short* __restrict__ Bt,
    float* __restrict__ C, int M, int N, int K) {
  __shared__ unsigned short As[BM * 64];
  __shared__ unsigned short Bs[BN * 64];
  constexpr int MT = BM / 32;
  constexpr int NT = BN / 32;
  constexpr int ACH = BM / 32;
  constexpr int BCH = BN / 32;
  int tid = threadIdx.x;
  int wave = tid >> 6, lane = tid & 63;
  int ln = lane & 15, hi = lane >> 4;
  int wm = wave & 1, wn = wave >> 1;
  int m0 = blockIdx.y * BM, n0 = blockIdx.x * BN;
  int lrow = lane >> 3, lcol = (lane & 7) * 8;

  floatx4 acc[MT][NT];
#pragma unroll
  for (int mt = 0; mt < MT; ++mt)
#pragma unroll
    for (int nt = 0; nt < NT; ++nt) acc[mt][nt] = (floatx4)(0.f);

  for (int k0 = 0; k0 < K; k0 += 64) {
#pragma unroll
    for (int i = 0; i < ACH; ++i) {
      int c = wave * ACH + i;
      gload16(A + (size_t)(m0 + c * 8 + lrow) * K + k0 + lcol, As + c * 512);
    }
#pragma unroll
    for (int i = 0; i < BCH; ++i) {
      int c = wave * BCH + i;
      gload16(Bt + (size_t)(n0 + c * 8 + lrow) * K + k0 + lcol, Bs + c * 512);
    }
    __syncthreads();
#pragma unroll
    for (int kb = 0; kb < 2; ++kb) {
      short8 a[MT], b[NT];
#pragma unroll
      for (int mt = 0; mt < MT; ++mt)
        a[mt] = *(const short8*)(As + (wm * (BM / 2) + mt * 16 + ln) * 64 +
                                 kb * 32 + hi * 8);
#pragma unroll
      for (int nt = 0; nt < NT; ++nt)
        b[nt] = *(const short8*)(Bs + (wn * (BN / 2) + nt * 16 + ln) * 64 +
                                 kb * 32 + hi * 8);
#pragma unroll
      for (int mt = 0; mt < MT; ++mt)
#pragma unroll
        for (int nt = 0; nt < NT; ++nt)
          acc[mt][nt] = __builtin_amdgcn_mfma_f32_16x16x32_bf16(
              a[mt], b[nt], acc[mt][nt], 0, 0, 0);
    }
    __syncthreads();
  }
#pragma unroll
  for (int mt = 0; mt < MT; ++mt)
#pragma unroll
    for (int nt = 0; nt < NT; ++nt) {
      int col = n0 + wn * (BN / 2) + nt * 16 + ln;
      int rowb = m0 + wm * (BM / 2) + mt * 16 + hi * 4;
#pragma unroll
      for (int r = 0; r < 4; ++r)
        C[(size_t)(rowb + r) * N + col] = acc[mt][nt][r];
    }
}

// ---------------------------------------------------------------------------
// Causal depthwise conv (K=4) + silu core.
// ---------------------------------------------------------------------------
__device__ __forceinline__ float conv_core(
    const float* __restrict__ xin, const float* __restrict__ w,
    int idx, int instride, int nch, float scale) {
  int t = idx / nch, ch = idx - t * nch;
  float acc = 0.f;
#pragma unroll
  for (int j = 0; j < 4; ++j) {
    int tt = t + j - 3;
    float xv = (tt >= 0) ? xin[(size_t)tt * instride + ch] : 0.f;
    acc = fmaf(xv, w[ch * 4 + j], acc);
  }
  return acc / (1.f + expf(-acc)) * scale;
}

// ---------------------------------------------------------------------------
// conv_all: q (bf16 out), k (f32+bf16 out), v (f32 out) + cumsum block.
// ---------------------------------------------------------------------------
__global__ __launch_bounds__(256) void conv_all(
    const float* __restrict__ xall, const float* __restrict__ convq,
    const float* __restrict__ convk, const float* __restrict__ convv,
    unsigned short* __restrict__ qs16, float* __restrict__ ks2,
    unsigned short* __restrict__ ks16, float* __restrict__ vs2,
    const float* __restrict__ glog, const float* __restrict__ beta,
    float* __restrict__ cs, float* __restrict__ wend) {
  int b = blockIdx.x, tid = threadIdx.x;
  if (b < 8192) {
    int idx = b * 256 + tid;
    qs16[idx] = f2bf(conv_core(xall, convq, idx, 6144, 2048,
                               0.08838834764831845f));
  } else if (b < 12288) {
    int idx = (b - 8192) * 256 + tid;
    float v = conv_core(xall + 2048, convk, idx, 6144, 1024, 1.0f);
    ks2[idx] = v;
    ks16[idx] = f2bf(v);
  } else if (b < 16384) {
    int idx = (b - 12288) * 256 + tid;
    vs2[idx] = conv_core(xall + 3072, convv, idx, 6144, 1024, 1.0f);
  } else {
    int idx = tid;
    int n = idx & 15;
    float acc = 0.f;
    for (int c = 0; c < CSZ; ++c) {
      acc += glog[(n * CSZ + c) * NHQ + (idx >> 4)];
      cs[idx * CSZ + c] = acc;
    }
    float G = acc;
    for (int c = 0; c < CSZ; ++c) {
      wend[idx * CSZ + c] =
          expf(G - cs[idx * CSZ + c]) * beta[(n * CSZ + c) * NHQ + (idx >> 4)];
    }
  }
}

// ---------------------------------------------------------------------------
// Gram increments per (h,n) via MFMA (blocks 0..255) + vtr (256..383).
// ---------------------------------------------------------------------------
__global__ __launch_bounds__(256) void dhb_kernel(
    const float* __restrict__ ks, const float* __restrict__ vs,
    const float* __restrict__ wend, float* __restrict__ dH,
    float* __restrict__ dB, unsigned short* __restrict__ vT16) {
  __shared__ uint4 smem4[4096];   // 64 KB
  int bid = blockIdx.x;
  int tid = threadIdx.x;

  if (bid >= 256) {
    // ---- vtr path ----
    float* t = (float*)smem4;
    int b = bid - 256;
    size_t gbase = ((size_t)(b >> 3)) * 65536 + ((size_t)(b & 7)) * 128;
#pragma unroll
    for (int g = 0; g < 8; ++g) {
      int i = tid + g * 256;
      int c = i >> 5, e4 = i & 31;
      float4 v = *(const float4*)(vs + gbase + (size_t)c * 1024 + e4 * 4);
      t[c * 132 + e4 * 4 + 0] = v.x;
      t[c * 132 + e4 * 4 + 1] = v.y;
      t[c * 132 + e4 * 4 + 2] = v.z;
      t[c * 132 + e4 * 4 + 3] = v.w;
    }
    __syncthreads();
    int e = tid >> 1, half = tid & 1;
    size_t obase = ((size_t)b << 13) + (size_t)e * 64 + half * 32;
#pragma unroll
    for (int cc = 0; cc < 8; ++cc) {
      int c0 = half * 32 + cc * 4;
      ushort4 u;
      u.x = f2bf(t[(c0 + 0) * 132 + e]);
      u.y = f2bf(t[(c0 + 1) * 132 + e]);
      u.z = f2bf(t[(c0 + 2) * 132 + e]);
      u.w = f2bf(t[(c0 + 3) * 132 + e]);
      *(ushort4*)(vT16 + obase + cc * 4) = u;
    }
    return;
  }

  // ---- dhb path ----
  unsigned short (*skF)[8192] = (unsigned short (*)[8192])smem4;
  unsigned short (*svF)[8192] =
      (unsigned short (*)[8192])((unsigned short*)smem4 + 16384);
  int h = bid >> 4, n = bid & 15;
  int hk = h >> 1;

#pragma unroll
  for (int p = 0; p < 4; ++p) {
    int t2 = tid + p * 256;
    int c0 = (t2 >> 7) << 3;
    int e = t2 & 127;
    int base = ((e >> 4) * 2 + (c0 >> 5)) * 512 +
               ((c0 & 31) >> 3) * 128 + (e & 15) * 8;
    unsigned short kh[8], kl[8], vh[8], vl[8];
#pragma unroll
    for (int j = 0; j < 8; ++j) {
      int c = c0 + j;
      float s = sqrtf(wend[bid * 64 + c]);
      size_t g = (size_t)(n * 64 + c) * 1024 + hk * 128 + e;
      float kf = s * ks[g];
      float vf = s * vs[g];
      unsigned short khh = f2bf(kf);
      kh[j] = khh; kl[j] = f2bf(kf - bf2f(khh));
      unsigned short vhh = f2bf(vf);
      vh[j] = vhh; vl[j] = f2bf(vf - bf2f(vhh));
    }
    *(uint4*)(&skF[0][base]) = *(uint4*)kh;
    *(uint4*)(&skF[1][base]) = *(uint4*)kl;
    *(uint4*)(&svF[0][base]) = *(uint4*)vh;
    *(uint4*)(&svF[1][base]) = *(uint4*)vl;
  }
  __syncthreads();

  int w = tid >> 6, lane = tid & 63;
  int ln = lane & 15, hi = lane >> 4;

  short8 ah[2][2], al[2][2];
#pragma unroll
  for (int mti = 0; mti < 2; ++mti) {
    int mt = w * 2 + mti;
#pragma unroll
    for (int ct = 0; ct < 2; ++ct) {
      ah[mti][ct] = *(const short8*)(&skF[0][((mt * 2 + ct) * 64 + lane) * 8]);
      al[mti][ct] = *(const short8*)(&skF[1][((mt * 2 + ct) * 64 + lane) * 8]);
    }
  }

  size_t gb = (size_t)bid << 14;
#pragma unroll
  for (int which = 0; which < 2; ++which) {
    const unsigned short (*BF)[8192] = which ? svF : skF;
    float* outp = which ? dB : dH;
#pragma unroll
    for (int nt = 0; nt < 8; ++nt) {
      floatx4 a0 = (floatx4)(0.f), a1 = (floatx4)(0.f);
#pragma unroll
      for (int ct = 0; ct < 2; ++ct) {
        short8 bh = *(const short8*)(&BF[0][((nt * 2 + ct) * 64 + lane) * 8]);
        short8 bl = *(const short8*)(&BF[1][((nt * 2 + ct) * 64 + lane) * 8]);
        a0 = __builtin_amdgcn_mfma_f32_16x16x32_bf16(ah[0][ct], bh, a0, 0, 0, 0);
        a0 = __builtin_amdgcn_mfma_f32_16x16x32_bf16(ah[0][ct], bl, a0, 0, 0, 0);
        a0 = __builtin_amdgcn_mfma_f32_16x16x32_bf16(al[0][ct], bh, a0, 0, 0, 0);
        a1 = __builtin_amdgcn_mfma_f32_16x16x32_bf16(ah[1][ct], bh, a1, 0, 0, 0);
        a1 = __builtin_amdgcn_mfma_f32_16x16x32_bf16(ah[1][ct], bl, a1, 0, 0, 0);
        a1 = __builtin_amdgcn_mfma_f32_16x16x32_bf16(al[1][ct], bh, a1, 0, 0, 0);
      }
      int e = nt * 16 + ln;
#pragma unroll
      for (int rg = 0; rg < 4; ++rg) {
        int d0 = (w * 2 + 0) * 16 + hi * 4 + rg;
        int d1 = (w * 2 + 1) * 16 + hi * 4 + rg;
        outp[gb + (size_t)d0 * 128 + e] = a0[rg];
        outp[gb + (size_t)d1 * 128 + e] = a1[rg];
      }
    }
  }
}

// ---------------------------------------------------------------------------
// Inter-chunk scan (in-place): store state at chunk start; A gets +ridge diag.
// ---------------------------------------------------------------------------
__global__ __launch_bounds__(256) void scan_kernel(
    float* __restrict__ dH, float* __restrict__ dB,
    const float* __restrict__ cs) {
  int idx = blockIdx.x * 256 + threadIdx.x;  // h*16384 + de
  int h = idx >> 14, de = idx & 16383;
  float Hs = 0.f, Bs = 0.f;
  bool diag = ((de % 129) == 0);
#pragma unroll 1
  for (int n = 0; n < NCH; ++n) {
    size_t off = ((size_t)(h * 16 + n) << 14) + de;
    float dh = dH[off], db = dB[off];
    dH[off] = diag ? (Hs + 0.02f) : Hs;
    dB[off] = Bs;
    float g = expf(cs[(h * 16 + n) * CSZ + (CSZ - 1)]);
    Hs = fmaf(g, Hs, dh);
    Bs = fmaf(g, Bs, db);
  }
}

// ---------------------------------------------------------------------------
// A (f32) -> split bf16 MFMA A-operand fragments + trace, 2-way row split.
// ---------------------------------------------------------------------------
__global__ __launch_bounds__(256) void afrag_kernel(
    float* __restrict__ Aall, float* __restrict__ traces2) {
  int bid = blockIdx.x;
  int bm = bid >> 1, hf = bid & 1;
  float* Ag = Aall + ((size_t)bm << 14);
  __shared__ float As[8192];
  int tid = threadIdx.x;
  const float* src = Ag + hf * 8192;
  for (int i = tid; i < 2048; i += 256)
    ((float4*)As)[i] = ((const float4*)src)[i];
  __syncthreads();
  if (tid < 64) {
    float tv = As[tid * 128 + hf * 64 + tid];
#pragma unroll
    for (int off = 32; off; off >>= 1) tv += __shfl_down(tv, off);
    if (tid == 0) traces2[bid] = tv;
  }
  unsigned short* Ah = (unsigned short*)Ag;
#pragma unroll
  for (int c8 = 0; c8 < 4; ++c8) {
    int l = tid * 32 + c8 * 8;           // local short offset [0,8192)
    int fl = l >> 9;                      // local frag [0,16)
    int frag = hf * 16 + fl;
    int mlane = (l >> 3) & 63;
    int m = ((frag >> 2) << 4) + (mlane & 15);
    int k = ((frag & 3) << 5) + ((mlane >> 4) << 3);
    int ml = m - hf * 64;
    unsigned short hi8[8], lo8[8];
#pragma unroll
    for (int j = 0; j < 8; ++j) {
      float a = As[ml * 128 + k + j];
      unsigned short h = f2bf(a);
      hi8[j] = h;
      lo8[j] = f2bf(a - bf2f(h));
    }
    *(uint4*)(Ah + hf * 16384 + l) = *(uint4*)hi8;
    *(uint4*)(Ah + hf * 16384 + 8192 + l) = *(uint4*)lo8;
  }
}

// ---------------------------------------------------------------------------
// Chebyshev solve via MFMA, 8-way column split, 256 thr (4 waves).
// Two launches of 1024 blocks (bm halves).  A-frag layout is the per-half
// plane layout written by afrag_kernel.
// ---------------------------------------------------------------------------
__global__ __launch_bounds__(256, 2) void cheb_kernel(
    const unsigned short* __restrict__ Afrag, const float* __restrict__ traces2,
    float* __restrict__ Ball, int bmoff) {
  int bid = blockIdx.x;
  int bm = (bid & 127) + bmoff;     // matrix id (h*16+n)
  int cb = bid >> 7;                // column eighth
  const unsigned short* __restrict__ Ah = Afrag + ((size_t)bm << 15);
  float* __restrict__ Bg = Ball + ((size_t)bm << 14);
  __shared__ unsigned short dT[2][2048];
  int tid = threadIdx.x;
  int w = tid >> 6, lane = tid & 63;
  int ln = lane & 15, q = lane >> 4;

  float lmax = traces2[2 * bm] + traces2[2 * bm + 1];
  const float lmin = 0.02f;
  float theta = 0.5f * (lmax + lmin);
  float delta = 0.5f * (lmax - lmin);
  float sigma1 = theta / delta;
  float rho = delta / theta;
  float invtheta = 1.f / theta;

  short8 afr[2][4][2];
#pragma unroll
  for (int mt = 0; mt < 2; ++mt)
#pragma unroll
    for (int kt = 0; kt < 4; ++kt) {
      int f = (w * 2 + mt) * 4 + kt;
      int hfA = f >> 4, fl = f & 15;
      const unsigned short* basef = Ah + hfA * 16384 + fl * 512 + (lane << 3);
      afr[mt][kt][0] = *(const short8*)(basef);
      afr[mt][kt][1] = *(const short8*)(basef + 8192);
    }

  int wrB[2];
#pragma unroll
  for (int mt = 0; mt < 2; ++mt)
    wrB[mt] = w * 512 + (((mt * 2 + (q >> 1)) & 3) * 16 + ln) * 8 +
              ((q & 1) << 2);

  float xx[2][4], rr[2][4], dd[2][4];
#pragma unroll
  for (int mt = 0; mt < 2; ++mt) {
#pragma unroll
    for (int rg = 0; rg < 4; ++rg) {
      float b = Bg[(w * 32 + mt * 16 + q * 4 + rg) * 128 + cb * 16 + ln];
      rr[mt][rg] = b;
      xx[mt][rg] = 0.f;
      dd[mt][rg] = b * invtheta;
    }
    unsigned int p01 = cvtpk(dd[mt][0], dd[mt][1]);
    unsigned int p23 = cvtpk(dd[mt][2], dd[mt][3]);
    dd[mt][0] = __uint_as_float(p01 << 16);
    dd[mt][1] = __uint_as_float(p01 & 0xffff0000u);
    dd[mt][2] = __uint_as_float(p23 << 16);
    dd[mt][3] = __uint_as_float(p23 & 0xffff0000u);
    uint2 pk; pk.x = p01; pk.y = p23;
    *(uint2*)(&dT[0][wrB[mt]]) = pk;
  }
  __syncthreads();

#pragma unroll 1
  for (int it = 0; it < 30; ++it) {
    const unsigned short* dTr = dT[it & 1];
    unsigned short* dTw = dT[(it & 1) ^ 1];
    floatx4 a0 = (floatx4)(0.f), a1 = (floatx4)(0.f);
#pragma unroll
    for (int kt = 0; kt < 4; ++kt) {
      short8 df = *(const short8*)(dTr + kt * 512 + lane * 8);
      a0 = __builtin_amdgcn_mfma_f32_16x16x32_bf16(afr[0][kt][0], df, a0, 0, 0, 0);
      a0 = __builtin_amdgcn_mfma_f32_16x16x32_bf16(afr[0][kt][1], df, a0, 0, 0, 0);
      a1 = __builtin_amdgcn_mfma_f32_16x16x32_bf16(afr[1][kt][0], df, a1, 0, 0, 0);
      a1 = __builtin_amdgcn_mfma_f32_16x16x32_bf16(afr[1][kt][1], df, a1, 0, 0, 0);
    }
    float rho_n = 1.f / (2.f * sigma1 - rho);
    float c1s = rho_n * rho;
    float c2s = 2.f * rho_n / delta;
#pragma unroll
    for (int mt = 0; mt < 2; ++mt) {
      float dn[4];
#pragma unroll
      for (int rg = 0; rg < 4; ++rg) {
        xx[mt][rg] += dd[mt][rg];
        rr[mt][rg] -= mt ? a1[rg] : a0[rg];
        dn[rg] = fmaf(c1s, dd[mt][rg], c2s * rr[mt][rg]);
      }
      unsigned int p01 = cvtpk(dn[0], dn[1]);
      unsigned int p23 = cvtpk(dn[2], dn[3]);
      dd[mt][0] = __uint_as_float(p01 << 16);
      dd[mt][1] = __uint_as_float(p01 & 0xffff0000u);
      dd[mt][2] = __uint_as_float(p23 << 16);
      dd[mt][3] = __uint_as_float(p23 & 0xffff0000u);
      uint2 pk; pk.x = p01; pk.y = p23;
      *(uint2*)(&dTw[wrB[mt]]) = pk;
    }
    rho = rho_n;
    __syncthreads();
  }

  unsigned short* Xf = (unsigned short*)Bg;
#pragma unroll
  for (int mt = 0; mt < 2; ++mt) {
    ushort4 h4, l4;
    unsigned short* hp = (unsigned short*)&h4;
    unsigned short* lp = (unsigned short*)&l4;
#pragma unroll
    for (int rg = 0; rg < 4; ++rg) {
      float xv = xx[mt][rg];
      unsigned short h = f2bf(xv);
      hp[rg] = h;
      lp[rg] = f2bf(xv - bf2f(h));
    }
    int lhi = wrB[mt];
    int llo = lhi + 2048;
    *(ushort4*)(Xf + ((lhi >> 5) << 8) + (cb << 5) + (lhi & 31)) = h4;
    *(ushort4*)(Xf + ((llo >> 5) << 8) + (cb << 5) + (llo & 31)) = l4;
  }
}

// ---------------------------------------------------------------------------
// Attention per (h,n), all-MFMA (blocks 0..255) + tcast(Wo) bn<16
// (blocks 256..511: bn=r&15, bk=r>>4, both in [0,16)).
// ---------------------------------------------------------------------------
__global__ __launch_bounds__(256) void attn_kernel(
    const unsigned short* __restrict__ q16, const unsigned short* __restrict__ k16,
    const unsigned short* __restrict__ vT16, const unsigned short* __restrict__ Xf,
    const float* __restrict__ vs, const float* __restrict__ cs,
    const float* __restrict__ beta, const float* __restrict__ alpha,
    float* __restrict__ o, const float* __restrict__ Wo,
    unsigned short* __restrict__ WtWo) {
  __shared__ __align__(16) float smem[11264];   // 45056 B union
  int tid = threadIdx.x;

  if (blockIdx.x >= 256) {
    int r = blockIdx.x - 256;        // 0..255
    int bn = r & 15, bk = r >> 4;    // bn in [0,16), bk in [0,16)
    tcast_fat(Wo, WtWo, 2048, 2048, bn, bk, tid, smem);
    return;
  }

  int bid = blockIdx.x;             // h*16+n
  int h = bid >> 4, n = bid & 15;
  int hk = h >> 1;
  unsigned short* qb = (unsigned short*)smem;          // 64*136
  unsigned short* kb = qb + 8704;                      // 64*136
  unsigned short* Sb = kb + 8704;                      // 64*72
  float* csL = smem + 11008;
  float* ecsL = csL + 64;
  float* betaL = ecsL + 64;
  float* alphaL = betaL + 64;
  int w = tid >> 6, lane = tid & 63;
  int ln = lane & 15, hi = lane >> 4;

  {
    size_t qgb = (((size_t)(n * 64)) * 16 + h) * 128;
    size_t kgb = (((size_t)(n * 64)) * 8 + hk) * 128;
#pragma unroll
    for (int g = 0; g < 4; ++g) {
      int i = tid + g * 256;
      int c = i >> 4, ch = i & 15;
      *(uint4*)(qb + c * 136 + ch * 8) =
          *(const uint4*)(q16 + qgb + (size_t)c * 2048 + ch * 8);
      *(uint4*)(kb + c * 136 + ch * 8) =
          *(const uint4*)(k16 + kgb + (size_t)c * 1024 + ch * 8);
    }
    if (tid < 64) {
      float cv = cs[bid * 64 + tid];
      csL[tid] = cv;
      ecsL[tid] = expf(cv);
      betaL[tid] = beta[(n * 64 + tid) * 16 + h];
      alphaL[tid] = alpha[(n * 64 + tid) * 16 + h];
    }
  }
  __syncthreads();

  short8 aq[4];
#pragma unroll
  for (int dt = 0; dt < 4; ++dt)
    aq[dt] = *(const short8*)(qb + (w * 16 + ln) * 136 + dt * 32 + hi * 8);

  // phase 1: o_inter = q @ X (hi+lo planes), then scale rows by exp(cs)
  const unsigned short* Xb = Xf + ((size_t)bid << 15);
  floatx4 acc[8];
#pragma unroll
  for (int et = 0; et < 8; ++et) {
    floatx4 a = (floatx4)(0.f);
#pragma unroll
    for (int dt = 0; dt < 4; ++dt) {
      int base = ((dt * 16 + (lane >> 2)) << 8) + (et << 5) + ((lane & 3) << 3);
      short8 xh = *(const short8*)(Xb + base);
      short8 xl = *(const short8*)(Xb + base + 16384);
      a = __builtin_amdgcn_mfma_f32_16x16x32_bf16(aq[dt], xh, a, 0, 0, 0);
      a = __builtin_amdgcn_mfma_f32_16x16x32_bf16(aq[dt], xl, a, 0, 0, 0);
    }
    acc[et] = a;
  }
#pragma unroll
  for (int et = 0; et < 8; ++et)
#pragma unroll
    for (int rg = 0; rg < 4; ++rg)
      acc[et][rg] *= ecsL[w * 16 + hi * 4 + rg];

  // phase 2: gated causal scores -> Sb (bf16), wave-local rows
#pragma unroll
  for (int jt = 0; jt < 4; ++jt) {
    if (jt <= w) {
      floatx4 s = (floatx4)(0.f);
#pragma unroll
      for (int dt = 0; dt < 4; ++dt) {
        short8 bk = *(const short8*)(kb + (jt * 16 + ln) * 136 + dt * 32 + hi * 8);
        s = __builtin_amdgcn_mfma_f32_16x16x32_bf16(aq[dt], bk, s, 0, 0, 0);
      }
      int j = jt * 16 + ln;
      float csj = csL[j], bj = betaL[j];
#pragma unroll
      for (int rg = 0; rg < 4; ++rg) {
        int c = w * 16 + hi * 4 + rg;
        float v = (j <= c) ? s[rg] * expf(csL[c] - csj) * bj : 0.f;
        Sb[c * 72 + j] = f2bf(v);
      }
    } else {
#pragma unroll
      for (int rg = 0; rg < 4; ++rg)
        Sb[(w * 16 + hi * 4 + rg) * 72 + jt * 16 + ln] = 0;
    }
  }

  // phase 3: O += S @ v
  const unsigned short* vTb = vT16 + ((size_t)(n * 8 + hk) << 13);
#pragma unroll
  for (int et = 0; et < 8; ++et) {
#pragma unroll
    for (int kt = 0; kt < 2; ++kt) {
      short8 as = *(const short8*)(Sb + (w * 16 + ln) * 72 + kt * 32 + hi * 8);
      short8 bv = *(const short8*)(vTb + (et * 16 + ln) * 64 + kt * 32 + hi * 8);
      acc[et] = __builtin_amdgcn_mfma_f32_16x16x32_bf16(as, bv, acc[et], 0, 0, 0);
    }
  }

  // epilogue: + alpha*v, store
#pragma unroll
  for (int et = 0; et < 8; ++et) {
#pragma unroll
    for (int rg = 0; rg < 4; ++rg) {
      int c = w * 16 + hi * 4 + rg, e = et * 16 + ln;
      size_t oaddr = (((size_t)(n * 64 + c)) * 16 + h) * 128 + e;
      size_t vaddr = (((size_t)(n * 64 + c)) * 8 + hk) * 128 + e;
      o[oaddr] = acc[et][rg] + alphaL[c] * vs[vaddr];
    }
  }
}

// ---------------------------------------------------------------------------
// rmso: tcast(Wo) bn>=16 (blocks 0..255) + gated RMSNorm (256..4351).
// ---------------------------------------------------------------------------
__global__ __launch_bounds__(256) void rmso_kernel(
    const float* __restrict__ o, const float* __restrict__ xall,
    const float* __restrict__ norm_w, unsigned short* __restrict__ onorm,
    const float* __restrict__ Wo, unsigned short* __restrict__ WtWo) {
  __shared__ float t[128 * 65];
  int b = blockIdx.x, tid = threadIdx.x;
  if (b < 256) {
    int bn = 16 + (b & 15), bk = b >> 4;   // bn in [16,32), bk in [0,16)
    tcast_fat(Wo, WtWo, 2048, 2048, bn, bk, tid, t);
  } else {
    int bb = b - 256;
    int wave = tid >> 6, lane = tid & 63;
    int row = bb * 4 + wave;         // t*16 + h
    size_t base = (size_t)row * HDIM;
    size_t gbase = (size_t)(row >> 4) * 6144 + 4096 + (size_t)(row & 15) * HDIM;
    float v0 = o[base + lane], v1 = o[base + lane + 64];
    float ss = fmaf(v0, v0, v1 * v1);
#pragma unroll
    for (int off = 32; off; off >>= 1) ss += __shfl_down(ss, off);
    ss = __shfl(ss, 0);
    float rinv = rsqrtf(ss * (1.f / 128.f) + 1e-6f);
    float g0 = xall[gbase + lane], g1 = xall[gbase + lane + 64];
    float s0 = g0 / (1.f + expf(-g0));
    float s1 = g1 / (1.f + expf(-g1));
    onorm[base + lane]      = f2bf(v0 * rinv * norm_w[lane] * s0);
    onorm[base + lane + 64] = f2bf(v1 * rinv * norm_w[lane + 64] * s1);
  }
}

// ---------------------------------------------------------------------------
extern "C" void kernel_launch(void* const* d_in, const int* in_sizes, int n_in,
                              void* d_out, int out_size, void* d_ws,
                              size_t ws_size, hipStream_t stream) {
  (void)in_sizes; (void)n_in; (void)out_size; (void)ws_size;
  const float* x      = (const float*)d_in[0];
  const float* Wq     = (const float*)d_in[1];
  const float* Wk     = (const float*)d_in[2];
  const float* Wv     = (const float*)d_in[3];
  const float* convq  = (const float*)d_in[4];
  const float* convk  = (const float*)d_in[5];
  const float* convv  = (const float*)d_in[6];
  const float* Wa     = (const float*)d_in[7];
  const float* A_log  = (const float*)d_in[8];
  const float* dtb    = (const float*)d_in[9];
  const float* Wb     = (const float*)d_in[10];
  const float* bbv    = (const float*)d_in[11];
  const float* Wal    = (const float*)d_in[12];
  const float* balv   = (const float*)d_in[13];
  const float* Wg     = (const float*)d_in[14];
  const float* norm_w = (const float*)d_in[15];
  const float* Wo     = (const float*)d_in[16];
  float* out = (float*)d_out;

  // workspace layout (float slots), ~88.5 MB total
  float* p = (float*)d_ws;
  float* xall  = p; p += 6291456;   // [L][6144]: q|k|v|g projections
  float* qslot = p; p += 2097152;   // carved: qs16 | ks16 | vT16 (bf16)
  float* ks2   = p; p += 1048576;   // + vs2: reused as WtWo (bf16) post-attn
  float* vs2   = p; p += 1048576;
  float* ob    = p; p += 2097152;
  float* glog  = p; p += 16384;
  float* beta  = p; p += 16384;
  float* alpha = p; p += 16384;
  float* csb   = p; p += 16384;
  float* wend  = p; p += 16384;
  float* traces= p; p += 16384;     // 512 used (per-half partials)
  float* dHn   = p; p += 4194304;   // -> A -> A-frags (bf16 hi/lo) in place
  float* dBn   = p; p += 4194304;   // -> B0 -> X-frags (bf16 hi/lo) in place
  unsigned short* xb16 = (unsigned short*)p; p += 1048576;

  unsigned short* qs16 = (unsigned short*)qslot;     // 1024*2048
  unsigned short* ks16 = qs16 + 2097152;             // 1024*1024
  unsigned short* vT16 = ks16 + 1048576;             // 128*128*64
  unsigned short* WtAll = (unsigned short*)dHn;      // 24 MB over dHn+dBn
  unsigned short* WtWo  = (unsigned short*)ks2;      // 8 MB over ks2+vs2
  unsigned short* onorm16 = xb16;                    // free after projections

  dim3 blk(256);
  // gates (4 ts/block) + fat tcast q|k|v|g + castbf(x)
  prep_kernel<<<2304, blk, 0, stream>>>(x, Wq, Wk, Wv, Wg, xb16, WtAll,
                                        Wa, Wb, Wal, A_log, dtb, bbv, balv,
                                        glog, beta, alpha);
  gemm_lds<128, 96><<<dim3(64, 8), blk, 0, stream>>>(xb16, WtAll, xall,
                                                     1024, 6144, 2048);
  // causal conv + silu (q scaled by HD^-0.5) + cumsum/w_end tail block
  conv_all<<<16385, blk, 0, stream>>>(xall, convq, convk, convv,
                                      qs16, ks2, ks16, vs2,
                                      glog, beta, csb, wend);
  // gram increments (MFMA) + v-transpose blocks, scan, A-frag prep, Chebyshev
  dhb_kernel<<<384, blk, 0, stream>>>(ks2, vs2, wend, dHn, dBn, vT16);
  scan_kernel<<<1024, blk, 0, stream>>>(dHn, dBn, csb);
  afrag_kernel<<<512, blk, 0, stream>>>(dHn, traces);
  cheb_kernel<<<1024, blk, 0, stream>>>((unsigned short*)dHn, traces, dBn, 0);
  cheb_kernel<<<1024, blk, 0, stream>>>((unsigned short*)dHn, traces, dBn, 128);
  // attention (all-MFMA) + tcast(Wo) rows < 1024 (ks2 region, dead)
  attn_kernel<<<512, blk, 0, stream>>>(qs16, ks16, vT16, (unsigned short*)dBn,
                                       vs2, csb, beta, alpha, ob, Wo, WtWo);
  // tcast(Wo) rows >= 1024 (vs2 region, dead after attn) + RMSNorm
  rmso_kernel<<<4352, blk, 0, stream>>>(ob, xall, norm_w, onorm16, Wo, WtWo);
  gemm_lds<64, 64><<<dim3(32, 16), blk, 0, stream>>>(onorm16, WtWo, out,
                                                     1024, 2048, 2048);
}

// Round 10
// 395.967 us; speedup vs baseline: 1.0733x; 1.0733x over previous
//
#include <hip/hip_runtime.h>
#include <math.h>

// GatedKalmaNet: B=1, L=1024, D=2048, HQ=16, HK=8, HD=128, CONV=4, CHUNK=64,
// Nc=16, NUM_ITER=30, RIDGE=0.02, EPS=1e-6.

#define LSEQ 1024
#define DM   2048
#define NHQ  16
#define NHK  8
#define HDIM 128
#define NCH  16
#define CSZ  64

typedef __attribute__((ext_vector_type(8))) short short8;
typedef __attribute__((ext_vector_type(4))) float floatx4;

// f32 -> bf16 RNE
__device__ __forceinline__ unsigned short f2bf(float f) {
  unsigned int u = __float_as_uint(f);
  u += 0x7fffu + ((u >> 16) & 1u);
  return (unsigned short)(u >> 16);
}
__device__ __forceinline__ float bf2f(unsigned short u) {
  return __uint_as_float(((unsigned int)u) << 16);
}

// packed f32x2 -> bf16x2 (RNE), lo half = first operand
__device__ __forceinline__ unsigned int cvtpk(float a, float b) {
  unsigned int r;
  asm("v_cvt_pk_bf16_f32 %0, %1, %2" : "=v"(r) : "v"(a), "v"(b));
  return r;
}

// async global->LDS, 16B per lane (wave-uniform LDS base + lane*16)
__device__ __forceinline__ void gload16(const unsigned short* g,
                                        unsigned short* l) {
  __builtin_amdgcn_global_load_lds(
      (const __attribute__((address_space(1))) unsigned int*)g,
      (__attribute__((address_space(3))) unsigned int*)l, 16, 0, 0);
}

// ---------------------------------------------------------------------------
// Fat transpose-cast: W[K][N] f32 -> Wt[N][K] bf16, one 128(k) x 64(n) tile.
// Valid tile ranges for 2048x2048: bk in [0,16), bn in [0,32).
// ---------------------------------------------------------------------------
__device__ __forceinline__ void tcast_fat(
    const float* __restrict__ W, unsigned short* __restrict__ Wt,
    int K, int N, int bn, int bk, int tid, float* __restrict__ t) {
  int k0 = bk * 128, n0 = bn * 64;
#pragma unroll
  for (int i = 0; i < 8; ++i) {
    int u = tid + i * 256;
    int r = u >> 4, c4 = u & 15;
    float4 v = *(const float4*)(W + (size_t)(k0 + r) * N + n0 + c4 * 4);
    float* dst = t + r * 65 + c4 * 4;
    dst[0] = v.x; dst[1] = v.y; dst[2] = v.z; dst[3] = v.w;
  }
  __syncthreads();
#pragma unroll
  for (int i = 0; i < 4; ++i) {
    int u2 = tid + i * 256;
    int klow = u2 & 7, nlow = (u2 >> 3) & 7;
    int khigh = (u2 >> 6) & 1, nhigh = (u2 >> 7) & 7;
    int k8 = (klow + khigh * 8) * 8;
    int nn = nlow + nhigh * 8;
    unsigned short o8[8];
#pragma unroll
    for (int j = 0; j < 8; ++j) o8[j] = f2bf(t[(k8 + j) * 65 + nn]);
    *(uint4*)(Wt + (size_t)(n0 + nn) * K + k0 + k8) = *(uint4*)o8;
  }
}

// ---------------------------------------------------------------------------
// prep: gates (0..767, one wave per (t,gate)) + tcast(Wq,Wk,Wv,Wg)
// (768..2303) + castbf(x) (2304..2815).
// Gates v3 (round-9 counters: VALUBusy 6.8%, occ 16%, dur 65us unchanged by
// the v2 VALU/LDS fix): the real cost was the W access pattern -- 16 p-lanes
// at 256B stride made every 16B lane-load a distinct cache line (~64 line
// requests per W-load instr, serialized in each block's TA).  v3: one WAVE
// per (t,g); lane l sweeps k=j*64+l reading x scalar (4B lane stride,
// coalesced) + the full W row W[k][0..16) as 4 float4 (64B lane stride,
// every line byte used).  16 indep FMA chains; 16x6 shfl reduce; lane 0
// applies nonlinearity.  768 short blocks, no LDS.
// ---------------------------------------------------------------------------
__global__ __launch_bounds__(256) void prep_kernel(
    const float* __restrict__ x, const float* __restrict__ Wq,
    const float* __restrict__ Wk, const float* __restrict__ Wv,
    const float* __restrict__ Wg, unsigned short* __restrict__ xb16,
    unsigned short* __restrict__ WtAll,
    const float* __restrict__ Wa, const float* __restrict__ Wbeta,
    const float* __restrict__ Wal, const float* __restrict__ A_log,
    const float* __restrict__ dtb, const float* __restrict__ bbv,
    const float* __restrict__ balv, float* __restrict__ glog,
    float* __restrict__ beta, float* __restrict__ alpha) {
  __shared__ float smem[128 * 65];
  int b = blockIdx.x, tid = threadIdx.x;
  if (b < 768) {
    int w = tid >> 6, lane = tid & 63;
    int wid = b * 4 + w;             // 0..3071
    int t = wid / 3;                 // timestep
    int g = wid - t * 3;             // gate id
    const float* W = (g == 0) ? Wa : (g == 1) ? Wbeta : Wal;
    const float* xrow = x + (size_t)t * 2048;
    float s[16];
#pragma unroll
    for (int h = 0; h < 16; ++h) s[h] = 0.f;
#pragma unroll 4
    for (int j = 0; j < 32; ++j) {
      int k = j * 64 + lane;
      float xv = xrow[k];
      const float* wr = W + (size_t)k * 16;
      float4 w0 = *(const float4*)(wr + 0);
      float4 w1 = *(const float4*)(wr + 4);
      float4 w2 = *(const float4*)(wr + 8);
      float4 w3 = *(const float4*)(wr + 12);
      s[0]  = fmaf(xv, w0.x, s[0]);
      s[1]  = fmaf(xv, w0.y, s[1]);
      s[2]  = fmaf(xv, w0.z, s[2]);
      s[3]  = fmaf(xv, w0.w, s[3]);
      s[4]  = fmaf(xv, w1.x, s[4]);
      s[5]  = fmaf(xv, w1.y, s[5]);
      s[6]  = fmaf(xv, w1.z, s[6]);
      s[7]  = fmaf(xv, w1.w, s[7]);
      s[8]  = fmaf(xv, w2.x, s[8]);
      s[9]  = fmaf(xv, w2.y, s[9]);
      s[10] = fmaf(xv, w2.z, s[10]);
      s[11] = fmaf(xv, w2.w, s[11]);
      s[12] = fmaf(xv, w3.x, s[12]);
      s[13] = fmaf(xv, w3.y, s[13]);
      s[14] = fmaf(xv, w3.z, s[14]);
      s[15] = fmaf(xv, w3.w, s[15]);
    }
#pragma unroll
    for (int h = 0; h < 16; ++h) {
      float v = s[h];
#pragma unroll
      for (int off = 32; off; off >>= 1) v += __shfl_down(v, off);
      s[h] = v;
    }
    if (lane == 0) {
      if (g == 0) {
#pragma unroll
        for (int h = 0; h < 16; ++h) {
          float za = s[h] + dtb[h];
          float sp = fmaxf(za, 0.f) + log1pf(expf(-fabsf(za)));
          glog[t * 16 + h] = -expf(A_log[h]) * sp;
        }
      } else if (g == 1) {
#pragma unroll
        for (int h = 0; h < 16; ++h)
          beta[t * 16 + h] = 1.f / (1.f + expf(-(s[h] + bbv[h])));
      } else {
#pragma unroll
        for (int h = 0; h < 16; ++h)
          alpha[t * 16 + h] = 1.f / (1.f + expf(-(s[h] + balv[h])));
      }
    }
  } else if (b < 2304) {
    int r = b - 768;
    if (r < 512) {
      tcast_fat(Wq, WtAll, 2048, 2048, r & 31, r >> 5, tid, smem);
    } else if (r < 768) {
      int q = r - 512;
      tcast_fat(Wk, WtAll + (size_t)2048 * 2048, 2048, 1024, q & 15, q >> 4,
                tid, smem);
    } else if (r < 1024) {
      int q = r - 768;
      tcast_fat(Wv, WtAll + (size_t)3072 * 2048, 2048, 1024, q & 15, q >> 4,
                tid, smem);
    } else {
      int q = r - 1024;
      tcast_fat(Wg, WtAll + (size_t)4096 * 2048, 2048, 2048, q & 31, q >> 5,
                tid, smem);
    }
  } else {
    int i0 = (b - 2304) * 1024 + tid;
#pragma unroll
    for (int i = 0; i < 4; ++i) {
      int idx = i0 + i * 256;
      float4 v = ((const float4*)x)[idx];
      ushort4 u;
      u.x = f2bf(v.x); u.y = f2bf(v.y); u.z = f2bf(v.z); u.w = f2bf(v.w);
      ((ushort4*)xb16)[idx] = u;
    }
  }
}

// ---------------------------------------------------------------------------
// bf16 MFMA GEMM, m97 structure: C[M,N](f32) = A[M,K](bf16) @ Bt[N,K]^T.
// BM/BN template, BK=64.  256 thr = 4 waves (2x2 over BM/2 x BN/2).
// Round-10: gemm1 reverted 128x96 -> 128x64 (768 blocks = 3/CU).  BN=96
// (512 blocks = 2/CU) regressed the timed total ~27us: at this 2-barrier
// structure, losing the 3rd co-resident block costs more barrier-drain
// overlap than the wider N-tile saves (matches learn_hip tile-space:
// 128x64-class 3/CU > wider tiles at 2/CU).
// ---------------------------------------------------------------------------
template <int BM, int BN>
__global__ __launch_bounds__(256) void gemm_lds(
    const unsigned short* __restrict__ A, const unsigned short* __restrict__ Bt,
    float* __restrict__ C, int M, int N, int K) {
  __shared__ unsigned short As[BM * 64];
  __shared__ unsigned short Bs[BN * 64];
  constexpr int MT = BM / 32;
  constexpr int NT = BN / 32;
  constexpr int ACH = BM / 32;
  constexpr int BCH = BN / 32;
  int tid = threadIdx.x;
  int wave = tid >> 6, lane = tid & 63;
  int ln = lane & 15, hi = lane >> 4;
  int wm = wave & 1, wn = wave >> 1;
  int m0 = blockIdx.y * BM, n0 = blockIdx.x * BN;
  int lrow = lane >> 3, lcol = (lane & 7) * 8;

  floatx4 acc[MT][NT];
#pragma unroll
  for (int mt = 0; mt < MT; ++mt)
#pragma unroll
    for (int nt = 0; nt < NT; ++nt) acc[mt][nt] = (floatx4)(0.f);

  for (int k0 = 0; k0 < K; k0 += 64) {
#pragma unroll
    for (int i = 0; i < ACH; ++i) {
      int c = wave * ACH + i;
      gload16(A + (size_t)(m0 + c * 8 + lrow) * K + k0 + lcol, As + c * 512);
    }
#pragma unroll
    for (int i = 0; i < BCH; ++i) {
      int c = wave * BCH + i;
      gload16(Bt + (size_t)(n0 + c * 8 + lrow) * K + k0 + lcol, Bs + c * 512);
    }
    __syncthreads();
#pragma unroll
    for (int kb = 0; kb < 2; ++kb) {
      short8 a[MT], b[NT];
#pragma unroll
      for (int mt = 0; mt < MT; ++mt)
        a[mt] = *(const short8*)(As + (wm * (BM / 2) + mt * 16 + ln) * 64 +
                                 kb * 32 + hi * 8);
#pragma unroll
      for (int nt = 0; nt < NT; ++nt)
        b[nt] = *(const short8*)(Bs + (wn * (BN / 2) + nt * 16 + ln) * 64 +
                                 kb * 32 + hi * 8);
#pragma unroll
      for (int mt = 0; mt < MT; ++mt)
#pragma unroll
        for (int nt = 0; nt < NT; ++nt)
          acc[mt][nt] = __builtin_amdgcn_mfma_f32_16x16x32_bf16(
              a[mt], b[nt], acc[mt][nt], 0, 0, 0);
    }
    __syncthreads();
  }
#pragma unroll
  for (int mt = 0; mt < MT; ++mt)
#pragma unroll
    for (int nt = 0; nt < NT; ++nt) {
      int col = n0 + wn * (BN / 2) + nt * 16 + ln;
      int rowb = m0 + wm * (BM / 2) + mt * 16 + hi * 4;
#pragma unroll
      for (int r = 0; r < 4; ++r)
        C[(size_t)(rowb + r) * N + col] = acc[mt][nt][r];
    }
}

// ---------------------------------------------------------------------------
// Causal depthwise conv (K=4) + silu core.
// ---------------------------------------------------------------------------
__device__ __forceinline__ float conv_core(
    const float* __restrict__ xin, const float* __restrict__ w,
    int idx, int instride, int nch, float scale) {
  int t = idx / nch, ch = idx - t * nch;
  float acc = 0.f;
#pragma unroll
  for (int j = 0; j < 4; ++j) {
    int tt = t + j - 3;
    float xv = (tt >= 0) ? xin[(size_t)tt * instride + ch] : 0.f;
    acc = fmaf(xv, w[ch * 4 + j], acc);
  }
  return acc / (1.f + expf(-acc)) * scale;
}

// ---------------------------------------------------------------------------
// conv_all: q (bf16 out), k (f32+bf16 out), v (f32 out) + cumsum block.
// ---------------------------------------------------------------------------
__global__ __launch_bounds__(256) void conv_all(
    const float* __restrict__ xall, const float* __restrict__ convq,
    const float* __restrict__ convk, const float* __restrict__ convv,
    unsigned short* __restrict__ qs16, float* __restrict__ ks2,
    unsigned short* __restrict__ ks16, float* __restrict__ vs2,
    const float* __restrict__ glog, const float* __restrict__ beta,
    float* __restrict__ cs, float* __restrict__ wend) {
  int b = blockIdx.x, tid = threadIdx.x;
  if (b < 8192) {
    int idx = b * 256 + tid;
    qs16[idx] = f2bf(conv_core(xall, convq, idx, 6144, 2048,
                               0.08838834764831845f));
  } else if (b < 12288) {
    int idx = (b - 8192) * 256 + tid;
    float v = conv_core(xall + 2048, convk, idx, 6144, 1024, 1.0f);
    ks2[idx] = v;
    ks16[idx] = f2bf(v);
  } else if (b < 16384) {
    int idx = (b - 12288) * 256 + tid;
    vs2[idx] = conv_core(xall + 3072, convv, idx, 6144, 1024, 1.0f);
  } else {
    int idx = tid;
    int n = idx & 15;
    float acc = 0.f;
    for (int c = 0; c < CSZ; ++c) {
      acc += glog[(n * CSZ + c) * NHQ + (idx >> 4)];
      cs[idx * CSZ + c] = acc;
    }
    float G = acc;
    for (int c = 0; c < CSZ; ++c) {
      wend[idx * CSZ + c] =
          expf(G - cs[idx * CSZ + c]) * beta[(n * CSZ + c) * NHQ + (idx >> 4)];
    }
  }
}

// ---------------------------------------------------------------------------
// Gram increments per (h,n) via MFMA (blocks 0..255) + vtr (256..383).
// ---------------------------------------------------------------------------
__global__ __launch_bounds__(256) void dhb_kernel(
    const float* __restrict__ ks, const float* __restrict__ vs,
    const float* __restrict__ wend, float* __restrict__ dH,
    float* __restrict__ dB, unsigned short* __restrict__ vT16) {
  __shared__ uint4 smem4[4096];   // 64 KB
  int bid = blockIdx.x;
  int tid = threadIdx.x;

  if (bid >= 256) {
    // ---- vtr path ----
    float* t = (float*)smem4;
    int b = bid - 256;
    size_t gbase = ((size_t)(b >> 3)) * 65536 + ((size_t)(b & 7)) * 128;
#pragma unroll
    for (int g = 0; g < 8; ++g) {
      int i = tid + g * 256;
      int c = i >> 5, e4 = i & 31;
      float4 v = *(const float4*)(vs + gbase + (size_t)c * 1024 + e4 * 4);
      t[c * 132 + e4 * 4 + 0] = v.x;
      t[c * 132 + e4 * 4 + 1] = v.y;
      t[c * 132 + e4 * 4 + 2] = v.z;
      t[c * 132 + e4 * 4 + 3] = v.w;
    }
    __syncthreads();
    int e = tid >> 1, half = tid & 1;
    size_t obase = ((size_t)b << 13) + (size_t)e * 64 + half * 32;
#pragma unroll
    for (int cc = 0; cc < 8; ++cc) {
      int c0 = half * 32 + cc * 4;
      ushort4 u;
      u.x = f2bf(t[(c0 + 0) * 132 + e]);
      u.y = f2bf(t[(c0 + 1) * 132 + e]);
      u.z = f2bf(t[(c0 + 2) * 132 + e]);
      u.w = f2bf(t[(c0 + 3) * 132 + e]);
      *(ushort4*)(vT16 + obase + cc * 4) = u;
    }
    return;
  }

  // ---- dhb path ----
  unsigned short (*skF)[8192] = (unsigned short (*)[8192])smem4;
  unsigned short (*svF)[8192] =
      (unsigned short (*)[8192])((unsigned short*)smem4 + 16384);
  int h = bid >> 4, n = bid & 15;
  int hk = h >> 1;

#pragma unroll
  for (int p = 0; p < 4; ++p) {
    int t2 = tid + p * 256;
    int c0 = (t2 >> 7) << 3;
    int e = t2 & 127;
    int base = ((e >> 4) * 2 + (c0 >> 5)) * 512 +
               ((c0 & 31) >> 3) * 128 + (e & 15) * 8;
    unsigned short kh[8], kl[8], vh[8], vl[8];
#pragma unroll
    for (int j = 0; j < 8; ++j) {
      int c = c0 + j;
      float s = sqrtf(wend[bid * 64 + c]);
      size_t g = (size_t)(n * 64 + c) * 1024 + hk * 128 + e;
      float kf = s * ks[g];
      float vf = s * vs[g];
      unsigned short khh = f2bf(kf);
      kh[j] = khh; kl[j] = f2bf(kf - bf2f(khh));
      unsigned short vhh = f2bf(vf);
      vh[j] = vhh; vl[j] = f2bf(vf - bf2f(vhh));
    }
    *(uint4*)(&skF[0][base]) = *(uint4*)kh;
    *(uint4*)(&skF[1][base]) = *(uint4*)kl;
    *(uint4*)(&svF[0][base]) = *(uint4*)vh;
    *(uint4*)(&svF[1][base]) = *(uint4*)vl;
  }
  __syncthreads();

  int w = tid >> 6, lane = tid & 63;
  int ln = lane & 15, hi = lane >> 4;

  short8 ah[2][2], al[2][2];
#pragma unroll
  for (int mti = 0; mti < 2; ++mti) {
    int mt = w * 2 + mti;
#pragma unroll
    for (int ct = 0; ct < 2; ++ct) {
      ah[mti][ct] = *(const short8*)(&skF[0][((mt * 2 + ct) * 64 + lane) * 8]);
      al[mti][ct] = *(const short8*)(&skF[1][((mt * 2 + ct) * 64 + lane) * 8]);
    }
  }

  size_t gb = (size_t)bid << 14;
#pragma unroll
  for (int which = 0; which < 2; ++which) {
    const unsigned short (*BF)[8192] = which ? svF : skF;
    float* outp = which ? dB : dH;
#pragma unroll
    for (int nt = 0; nt < 8; ++nt) {
      floatx4 a0 = (floatx4)(0.f), a1 = (floatx4)(0.f);
#pragma unroll
      for (int ct = 0; ct < 2; ++ct) {
        short8 bh = *(const short8*)(&BF[0][((nt * 2 + ct) * 64 + lane) * 8]);
        short8 bl = *(const short8*)(&BF[1][((nt * 2 + ct) * 64 + lane) * 8]);
        a0 = __builtin_amdgcn_mfma_f32_16x16x32_bf16(ah[0][ct], bh, a0, 0, 0, 0);
        a0 = __builtin_amdgcn_mfma_f32_16x16x32_bf16(ah[0][ct], bl, a0, 0, 0, 0);
        a0 = __builtin_amdgcn_mfma_f32_16x16x32_bf16(al[0][ct], bh, a0, 0, 0, 0);
        a1 = __builtin_amdgcn_mfma_f32_16x16x32_bf16(ah[1][ct], bh, a1, 0, 0, 0);
        a1 = __builtin_amdgcn_mfma_f32_16x16x32_bf16(ah[1][ct], bl, a1, 0, 0, 0);
        a1 = __builtin_amdgcn_mfma_f32_16x16x32_bf16(al[1][ct], bh, a1, 0, 0, 0);
      }
      int e = nt * 16 + ln;
#pragma unroll
      for (int rg = 0; rg < 4; ++rg) {
        int d0 = (w * 2 + 0) * 16 + hi * 4 + rg;
        int d1 = (w * 2 + 1) * 16 + hi * 4 + rg;
        outp[gb + (size_t)d0 * 128 + e] = a0[rg];
        outp[gb + (size_t)d1 * 128 + e] = a1[rg];
      }
    }
  }
}

// ---------------------------------------------------------------------------
// Inter-chunk scan (in-place): store state at chunk start; A gets +ridge diag.
// ---------------------------------------------------------------------------
__global__ __launch_bounds__(256) void scan_kernel(
    float* __restrict__ dH, float* __restrict__ dB,
    const float* __restrict__ cs) {
  int idx = blockIdx.x * 256 + threadIdx.x;  // h*16384 + de
  int h = idx >> 14, de = idx & 16383;
  float Hs = 0.f, Bs = 0.f;
  bool diag = ((de % 129) == 0);
#pragma unroll 1
  for (int n = 0; n < NCH; ++n) {
    size_t off = ((size_t)(h * 16 + n) << 14) + de;
    float dh = dH[off], db = dB[off];
    dH[off] = diag ? (Hs + 0.02f) : Hs;
    dB[off] = Bs;
    float g = expf(cs[(h * 16 + n) * CSZ + (CSZ - 1)]);
    Hs = fmaf(g, Hs, dh);
    Bs = fmaf(g, Bs, db);
  }
}

// ---------------------------------------------------------------------------
// A (f32) -> split bf16 MFMA A-operand fragments + trace, 2-way row split.
// ---------------------------------------------------------------------------
__global__ __launch_bounds__(256) void afrag_kernel(
    float* __restrict__ Aall, float* __restrict__ traces2) {
  int bid = blockIdx.x;
  int bm = bid >> 1, hf = bid & 1;
  float* Ag = Aall + ((size_t)bm << 14);
  __shared__ float As[8192];
  int tid = threadIdx.x;
  const float* src = Ag + hf * 8192;
  for (int i = tid; i < 2048; i += 256)
    ((float4*)As)[i] = ((const float4*)src)[i];
  __syncthreads();
  if (tid < 64) {
    float tv = As[tid * 128 + hf * 64 + tid];
#pragma unroll
    for (int off = 32; off; off >>= 1) tv += __shfl_down(tv, off);
    if (tid == 0) traces2[bid] = tv;
  }
  unsigned short* Ah = (unsigned short*)Ag;
#pragma unroll
  for (int c8 = 0; c8 < 4; ++c8) {
    int l = tid * 32 + c8 * 8;           // local short offset [0,8192)
    int fl = l >> 9;                      // local frag [0,16)
    int frag = hf * 16 + fl;
    int mlane = (l >> 3) & 63;
    int m = ((frag >> 2) << 4) + (mlane & 15);
    int k = ((frag & 3) << 5) + ((mlane >> 4) << 3);
    int ml = m - hf * 64;
    unsigned short hi8[8], lo8[8];
#pragma unroll
    for (int j = 0; j < 8; ++j) {
      float a = As[ml * 128 + k + j];
      unsigned short h = f2bf(a);
      hi8[j] = h;
      lo8[j] = f2bf(a - bf2f(h));
    }
    *(uint4*)(Ah + hf * 16384 + l) = *(uint4*)hi8;
    *(uint4*)(Ah + hf * 16384 + 8192 + l) = *(uint4*)lo8;
  }
}

// ---------------------------------------------------------------------------
// Chebyshev solve via MFMA, 8-way column split, 256 thr (4 waves).
// Two launches of 1024 blocks (bm halves).  A-frag layout is the per-half
// plane layout written by afrag_kernel.
// ---------------------------------------------------------------------------
__global__ __launch_bounds__(256, 2) void cheb_kernel(
    const unsigned short* __restrict__ Afrag, const float* __restrict__ traces2,
    float* __restrict__ Ball, int bmoff) {
  int bid = blockIdx.x;
  int bm = (bid & 127) + bmoff;     // matrix id (h*16+n)
  int cb = bid >> 7;                // column eighth
  const unsigned short* __restrict__ Ah = Afrag + ((size_t)bm << 15);
  float* __restrict__ Bg = Ball + ((size_t)bm << 14);
  __shared__ unsigned short dT[2][2048];
  int tid = threadIdx.x;
  int w = tid >> 6, lane = tid & 63;
  int ln = lane & 15, q = lane >> 4;

  float lmax = traces2[2 * bm] + traces2[2 * bm + 1];
  const float lmin = 0.02f;
  float theta = 0.5f * (lmax + lmin);
  float delta = 0.5f * (lmax - lmin);
  float sigma1 = theta / delta;
  float rho = delta / theta;
  float invtheta = 1.f / theta;

  short8 afr[2][4][2];
#pragma unroll
  for (int mt = 0; mt < 2; ++mt)
#pragma unroll
    for (int kt = 0; kt < 4; ++kt) {
      int f = (w * 2 + mt) * 4 + kt;
      int hfA = f >> 4, fl = f & 15;
      const unsigned short* basef = Ah + hfA * 16384 + fl * 512 + (lane << 3);
      afr[mt][kt][0] = *(const short8*)(basef);
      afr[mt][kt][1] = *(const short8*)(basef + 8192);
    }

  int wrB[2];
#pragma unroll
  for (int mt = 0; mt < 2; ++mt)
    wrB[mt] = w * 512 + (((mt * 2 + (q >> 1)) & 3) * 16 + ln) * 8 +
              ((q & 1) << 2);

  float xx[2][4], rr[2][4], dd[2][4];
#pragma unroll
  for (int mt = 0; mt < 2; ++mt) {
#pragma unroll
    for (int rg = 0; rg < 4; ++rg) {
      float b = Bg[(w * 32 + mt * 16 + q * 4 + rg) * 128 + cb * 16 + ln];
      rr[mt][rg] = b;
      xx[mt][rg] = 0.f;
      dd[mt][rg] = b * invtheta;
    }
    unsigned int p01 = cvtpk(dd[mt][0], dd[mt][1]);
    unsigned int p23 = cvtpk(dd[mt][2], dd[mt][3]);
    dd[mt][0] = __uint_as_float(p01 << 16);
    dd[mt][1] = __uint_as_float(p01 & 0xffff0000u);
    dd[mt][2] = __uint_as_float(p23 << 16);
    dd[mt][3] = __uint_as_float(p23 & 0xffff0000u);
    uint2 pk; pk.x = p01; pk.y = p23;
    *(uint2*)(&dT[0][wrB[mt]]) = pk;
  }
  __syncthreads();

#pragma unroll 1
  for (int it = 0; it < 30; ++it) {
    const unsigned short* dTr = dT[it & 1];
    unsigned short* dTw = dT[(it & 1) ^ 1];
    floatx4 a0 = (floatx4)(0.f), a1 = (floatx4)(0.f);
#pragma unroll
    for (int kt = 0; kt < 4; ++kt) {
      short8 df = *(const short8*)(dTr + kt * 512 + lane * 8);
      a0 = __builtin_amdgcn_mfma_f32_16x16x32_bf16(afr[0][kt][0], df, a0, 0, 0, 0);
      a0 = __builtin_amdgcn_mfma_f32_16x16x32_bf16(afr[0][kt][1], df, a0, 0, 0, 0);
      a1 = __builtin_amdgcn_mfma_f32_16x16x32_bf16(afr[1][kt][0], df, a1, 0, 0, 0);
      a1 = __builtin_amdgcn_mfma_f32_16x16x32_bf16(afr[1][kt][1], df, a1, 0, 0, 0);
    }
    float rho_n = 1.f / (2.f * sigma1 - rho);
    float c1s = rho_n * rho;
    float c2s = 2.f * rho_n / delta;
#pragma unroll
    for (int mt = 0; mt < 2; ++mt) {
      float dn[4];
#pragma unroll
      for (int rg = 0; rg < 4; ++rg) {
        xx[mt][rg] += dd[mt][rg];
        rr[mt][rg] -= mt ? a1[rg] : a0[rg];
        dn[rg] = fmaf(c1s, dd[mt][rg], c2s * rr[mt][rg]);
      }
      unsigned int p01 = cvtpk(dn[0], dn[1]);
      unsigned int p23 = cvtpk(dn[2], dn[3]);
      dd[mt][0] = __uint_as_float(p01 << 16);
      dd[mt][1] = __uint_as_float(p01 & 0xffff0000u);
      dd[mt][2] = __uint_as_float(p23 << 16);
      dd[mt][3] = __uint_as_float(p23 & 0xffff0000u);
      uint2 pk; pk.x = p01; pk.y = p23;
      *(uint2*)(&dTw[wrB[mt]]) = pk;
    }
    rho = rho_n;
    __syncthreads();
  }

  unsigned short* Xf = (unsigned short*)Bg;
#pragma unroll
  for (int mt = 0; mt < 2; ++mt) {
    ushort4 h4, l4;
    unsigned short* hp = (unsigned short*)&h4;
    unsigned short* lp = (unsigned short*)&l4;
#pragma unroll
    for (int rg = 0; rg < 4; ++rg) {
      float xv = xx[mt][rg];
      unsigned short h = f2bf(xv);
      hp[rg] = h;
      lp[rg] = f2bf(xv - bf2f(h));
    }
    int lhi = wrB[mt];
    int llo = lhi + 2048;
    *(ushort4*)(Xf + ((lhi >> 5) << 8) + (cb << 5) + (lhi & 31)) = h4;
    *(ushort4*)(Xf + ((llo >> 5) << 8) + (cb << 5) + (llo & 31)) = l4;
  }
}

// ---------------------------------------------------------------------------
// Attention per (h,n), all-MFMA (blocks 0..255) + tcast(Wo) bn<16
// (blocks 256..511: bn=r&15, bk=r>>4, both in [0,16)).
// ---------------------------------------------------------------------------
__global__ __launch_bounds__(256) void attn_kernel(
    const unsigned short* __restrict__ q16, const unsigned short* __restrict__ k16,
    const unsigned short* __restrict__ vT16, const unsigned short* __restrict__ Xf,
    const float* __restrict__ vs, const float* __restrict__ cs,
    const float* __restrict__ beta, const float* __restrict__ alpha,
    float* __restrict__ o, const float* __restrict__ Wo,
    unsigned short* __restrict__ WtWo) {
  __shared__ __align__(16) float smem[11264];   // 45056 B union
  int tid = threadIdx.x;

  if (blockIdx.x >= 256) {
    int r = blockIdx.x - 256;        // 0..255
    int bn = r & 15, bk = r >> 4;    // bn in [0,16), bk in [0,16)
    tcast_fat(Wo, WtWo, 2048, 2048, bn, bk, tid, smem);
    return;
  }

  int bid = blockIdx.x;             // h*16+n
  int h = bid >> 4, n = bid & 15;
  int hk = h >> 1;
  unsigned short* qb = (unsigned short*)smem;          // 64*136
  unsigned short* kb = qb + 8704;                      // 64*136
  unsigned short* Sb = kb + 8704;                      // 64*72
  float* csL = smem + 11008;
  float* ecsL = csL + 64;
  float* betaL = ecsL + 64;
  float* alphaL = betaL + 64;
  int w = tid >> 6, lane = tid & 63;
  int ln = lane & 15, hi = lane >> 4;

  {
    size_t qgb = (((size_t)(n * 64)) * 16 + h) * 128;
    size_t kgb = (((size_t)(n * 64)) * 8 + hk) * 128;
#pragma unroll
    for (int g = 0; g < 4; ++g) {
      int i = tid + g * 256;
      int c = i >> 4, ch = i & 15;
      *(uint4*)(qb + c * 136 + ch * 8) =
          *(const uint4*)(q16 + qgb + (size_t)c * 2048 + ch * 8);
      *(uint4*)(kb + c * 136 + ch * 8) =
          *(const uint4*)(k16 + kgb + (size_t)c * 1024 + ch * 8);
    }
    if (tid < 64) {
      float cv = cs[bid * 64 + tid];
      csL[tid] = cv;
      ecsL[tid] = expf(cv);
      betaL[tid] = beta[(n * 64 + tid) * 16 + h];
      alphaL[tid] = alpha[(n * 64 + tid) * 16 + h];
    }
  }
  __syncthreads();

  short8 aq[4];
#pragma unroll
  for (int dt = 0; dt < 4; ++dt)
    aq[dt] = *(const short8*)(qb + (w * 16 + ln) * 136 + dt * 32 + hi * 8);

  // phase 1: o_inter = q @ X (hi+lo planes), then scale rows by exp(cs)
  const unsigned short* Xb = Xf + ((size_t)bid << 15);
  floatx4 acc[8];
#pragma unroll
  for (int et = 0; et < 8; ++et) {
    floatx4 a = (floatx4)(0.f);
#pragma unroll
    for (int dt = 0; dt < 4; ++dt) {
      int base = ((dt * 16 + (lane >> 2)) << 8) + (et << 5) + ((lane & 3) << 3);
      short8 xh = *(const short8*)(Xb + base);
      short8 xl = *(const short8*)(Xb + base + 16384);
      a = __builtin_amdgcn_mfma_f32_16x16x32_bf16(aq[dt], xh, a, 0, 0, 0);
      a = __builtin_amdgcn_mfma_f32_16x16x32_bf16(aq[dt], xl, a, 0, 0, 0);
    }
    acc[et] = a;
  }
#pragma unroll
  for (int et = 0; et < 8; ++et)
#pragma unroll
    for (int rg = 0; rg < 4; ++rg)
      acc[et][rg] *= ecsL[w * 16 + hi * 4 + rg];

  // phase 2: gated causal scores -> Sb (bf16), wave-local rows
#pragma unroll
  for (int jt = 0; jt < 4; ++jt) {
    if (jt <= w) {
      floatx4 s = (floatx4)(0.f);
#pragma unroll
      for (int dt = 0; dt < 4; ++dt) {
        short8 bk = *(const short8*)(kb + (jt * 16 + ln) * 136 + dt * 32 + hi * 8);
        s = __builtin_amdgcn_mfma_f32_16x16x32_bf16(aq[dt], bk, s, 0, 0, 0);
      }
      int j = jt * 16 + ln;
      float csj = csL[j], bj = betaL[j];
#pragma unroll
      for (int rg = 0; rg < 4; ++rg) {
        int c = w * 16 + hi * 4 + rg;
        float v = (j <= c) ? s[rg] * expf(csL[c] - csj) * bj : 0.f;
        Sb[c * 72 + j] = f2bf(v);
      }
    } else {
#pragma unroll
      for (int rg = 0; rg < 4; ++rg)
        Sb[(w * 16 + hi * 4 + rg) * 72 + jt * 16 + ln] = 0;
    }
  }

  // phase 3: O += S @ v
  const unsigned short* vTb = vT16 + ((size_t)(n * 8 + hk) << 13);
#pragma unroll
  for (int et = 0; et < 8; ++et) {
#pragma unroll
    for (int kt = 0; kt < 2; ++kt) {
      short8 as = *(const short8*)(Sb + (w * 16 + ln) * 72 + kt * 32 + hi * 8);
      short8 bv = *(const short8*)(vTb + (et * 16 + ln) * 64 + kt * 32 + hi * 8);
      acc[et] = __builtin_amdgcn_mfma_f32_16x16x32_bf16(as, bv, acc[et], 0, 0, 0);
    }
  }

  // epilogue: + alpha*v, store
#pragma unroll
  for (int et = 0; et < 8; ++et) {
#pragma unroll
    for (int rg = 0; rg < 4; ++rg) {
      int c = w * 16 + hi * 4 + rg, e = et * 16 + ln;
      size_t oaddr = (((size_t)(n * 64 + c)) * 16 + h) * 128 + e;
      size_t vaddr = (((size_t)(n * 64 + c)) * 8 + hk) * 128 + e;
      o[oaddr] = acc[et][rg] + alphaL[c] * vs[vaddr];
    }
  }
}

// ---------------------------------------------------------------------------
// rmso: tcast(Wo) bn>=16 (blocks 0..255) + gated RMSNorm (256..4351).
// ---------------------------------------------------------------------------
__global__ __launch_bounds__(256) void rmso_kernel(
    const float* __restrict__ o, const float* __restrict__ xall,
    const float* __restrict__ norm_w, unsigned short* __restrict__ onorm,
    const float* __restrict__ Wo, unsigned short* __restrict__ WtWo) {
  __shared__ float t[128 * 65];
  int b = blockIdx.x, tid = threadIdx.x;
  if (b < 256) {
    int bn = 16 + (b & 15), bk = b >> 4;   // bn in [16,32), bk in [0,16)
    tcast_fat(Wo, WtWo, 2048, 2048, bn, bk, tid, t);
  } else {
    int bb = b - 256;
    int wave = tid >> 6, lane = tid & 63;
    int row = bb * 4 + wave;         // t*16 + h
    size_t base = (size_t)row * HDIM;
    size_t gbase = (size_t)(row >> 4) * 6144 + 4096 + (size_t)(row & 15) * HDIM;
    float v0 = o[base + lane], v1 = o[base + lane + 64];
    float ss = fmaf(v0, v0, v1 * v1);
#pragma unroll
    for (int off = 32; off; off >>= 1) ss += __shfl_down(ss, off);
    ss = __shfl(ss, 0);
    float rinv = rsqrtf(ss * (1.f / 128.f) + 1e-6f);
    float g0 = xall[gbase + lane], g1 = xall[gbase + lane + 64];
    float s0 = g0 / (1.f + expf(-g0));
    float s1 = g1 / (1.f + expf(-g1));
    onorm[base + lane]      = f2bf(v0 * rinv * norm_w[lane] * s0);
    onorm[base + lane + 64] = f2bf(v1 * rinv * norm_w[lane + 64] * s1);
  }
}

// ---------------------------------------------------------------------------
extern "C" void kernel_launch(void* const* d_in, const int* in_sizes, int n_in,
                              void* d_out, int out_size, void* d_ws,
                              size_t ws_size, hipStream_t stream) {
  (void)in_sizes; (void)n_in; (void)out_size; (void)ws_size;
  const float* x      = (const float*)d_in[0];
  const float* Wq     = (const float*)d_in[1];
  const float* Wk     = (const float*)d_in[2];
  const float* Wv     = (const float*)d_in[3];
  const float* convq  = (const float*)d_in[4];
  const float* convk  = (const float*)d_in[5];
  const float* convv  = (const float*)d_in[6];
  const float* Wa     = (const float*)d_in[7];
  const float* A_log  = (const float*)d_in[8];
  const float* dtb    = (const float*)d_in[9];
  const float* Wb     = (const float*)d_in[10];
  const float* bbv    = (const float*)d_in[11];
  const float* Wal    = (const float*)d_in[12];
  const float* balv   = (const float*)d_in[13];
  const float* Wg     = (const float*)d_in[14];
  const float* norm_w = (const float*)d_in[15];
  const float* Wo     = (const float*)d_in[16];
  float* out = (float*)d_out;

  // workspace layout (float slots), ~88.5 MB total
  float* p = (float*)d_ws;
  float* xall  = p; p += 6291456;   // [L][6144]: q|k|v|g projections
  float* qslot = p; p += 2097152;   // carved: qs16 | ks16 | vT16 (bf16)
  float* ks2   = p; p += 1048576;   // + vs2: reused as WtWo (bf16) post-attn
  float* vs2   = p; p += 1048576;
  float* ob    = p; p += 2097152;
  float* glog  = p; p += 16384;
  float* beta  = p; p += 16384;
  float* alpha = p; p += 16384;
  float* csb   = p; p += 16384;
  float* wend  = p; p += 16384;
  float* traces= p; p += 16384;     // 512 used (per-half partials)
  float* dHn   = p; p += 4194304;   // -> A -> A-frags (bf16 hi/lo) in place
  float* dBn   = p; p += 4194304;   // -> B0 -> X-frags (bf16 hi/lo) in place
  unsigned short* xb16 = (unsigned short*)p; p += 1048576;

  unsigned short* qs16 = (unsigned short*)qslot;     // 1024*2048
  unsigned short* ks16 = qs16 + 2097152;             // 1024*1024
  unsigned short* vT16 = ks16 + 1048576;             // 128*128*64
  unsigned short* WtAll = (unsigned short*)dHn;      // 24 MB over dHn+dBn
  unsigned short* WtWo  = (unsigned short*)ks2;      // 8 MB over ks2+vs2
  unsigned short* onorm16 = xb16;                    // free after projections

  dim3 blk(256);
  // gates (wave per (t,g), coalesced) + fat tcast q|k|v|g + castbf(x)
  prep_kernel<<<2816, blk, 0, stream>>>(x, Wq, Wk, Wv, Wg, xb16, WtAll,
                                        Wa, Wb, Wal, A_log, dtb, bbv, balv,
                                        glog, beta, alpha);
  gemm_lds<128, 64><<<dim3(96, 8), blk, 0, stream>>>(xb16, WtAll, xall,
                                                     1024, 6144, 2048);
  // causal conv + silu (q scaled by HD^-0.5) + cumsum/w_end tail block
  conv_all<<<16385, blk, 0, stream>>>(xall, convq, convk, convv,
                                      qs16, ks2, ks16, vs2,
                                      glog, beta, csb, wend);
  // gram increments (MFMA) + v-transpose blocks, scan, A-frag prep, Chebyshev
  dhb_kernel<<<384, blk, 0, stream>>>(ks2, vs2, wend, dHn, dBn, vT16);
  scan_kernel<<<1024, blk, 0, stream>>>(dHn, dBn, csb);
  afrag_kernel<<<512, blk, 0, stream>>>(dHn, traces);
  cheb_kernel<<<1024, blk, 0, stream>>>((unsigned short*)dHn, traces, dBn, 0);
  cheb_kernel<<<1024, blk, 0, stream>>>((unsigned short*)dHn, traces, dBn, 128);
  // attention (all-MFMA) + tcast(Wo) rows < 1024 (ks2 region, dead)
  attn_kernel<<<512, blk, 0, stream>>>(qs16, ks16, vT16, (unsigned short*)dBn,
                                       vs2, csb, beta, alpha, ob, Wo, WtWo);
  // tcast(Wo) rows >= 1024 (vs2 region, dead after attn) + RMSNorm
  rmso_kernel<<<4352, blk, 0, stream>>>(ob, xall, norm_w, onorm16, Wo, WtWo);
  gemm_lds<64, 64><<<dim3(32, 16), blk, 0, stream>>>(onorm16, WtWo, out,
                                                     1024, 2048, 2048);
}

// Round 11
// 381.904 us; speedup vs baseline: 1.1128x; 1.0368x over previous
//
#include <hip/hip_runtime.h>
#include <math.h>

// GatedKalmaNet: B=1, L=1024, D=2048, HQ=16, HK=8, HD=128, CONV=4, CHUNK=64,
// Nc=16, NUM_ITER=30, RIDGE=0.02, EPS=1e-6.

#define LSEQ 1024
#define DM   2048
#define NHQ  16
#define NHK  8
#define HDIM 128
#define NCH  16
#define CSZ  64

typedef __attribute__((ext_vector_type(8))) short short8;
typedef __attribute__((ext_vector_type(4))) float floatx4;

// f32 -> bf16 RNE
__device__ __forceinline__ unsigned short f2bf(float f) {
  unsigned int u = __float_as_uint(f);
  u += 0x7fffu + ((u >> 16) & 1u);
  return (unsigned short)(u >> 16);
}
__device__ __forceinline__ float bf2f(unsigned short u) {
  return __uint_as_float(((unsigned int)u) << 16);
}

// packed f32x2 -> bf16x2 (RNE), lo half = first operand
__device__ __forceinline__ unsigned int cvtpk(float a, float b) {
  unsigned int r;
  asm("v_cvt_pk_bf16_f32 %0, %1, %2" : "=v"(r) : "v"(a), "v"(b));
  return r;
}

// async global->LDS, 16B per lane (wave-uniform LDS base + lane*16)
__device__ __forceinline__ void gload16(const unsigned short* g,
                                        unsigned short* l) {
  __builtin_amdgcn_global_load_lds(
      (const __attribute__((address_space(1))) unsigned int*)g,
      (__attribute__((address_space(3))) unsigned int*)l, 16, 0, 0);
}

// ---------------------------------------------------------------------------
// Fat transpose-cast: W[K][N] f32 -> Wt[N][K] bf16, one 128(k) x 64(n) tile.
// Valid tile ranges for 2048x2048: bk in [0,16), bn in [0,32).
// ---------------------------------------------------------------------------
__device__ __forceinline__ void tcast_fat(
    const float* __restrict__ W, unsigned short* __restrict__ Wt,
    int K, int N, int bn, int bk, int tid, float* __restrict__ t) {
  int k0 = bk * 128, n0 = bn * 64;
#pragma unroll
  for (int i = 0; i < 8; ++i) {
    int u = tid + i * 256;
    int r = u >> 4, c4 = u & 15;
    float4 v = *(const float4*)(W + (size_t)(k0 + r) * N + n0 + c4 * 4);
    float* dst = t + r * 65 + c4 * 4;
    dst[0] = v.x; dst[1] = v.y; dst[2] = v.z; dst[3] = v.w;
  }
  __syncthreads();
#pragma unroll
  for (int i = 0; i < 4; ++i) {
    int u2 = tid + i * 256;
    int klow = u2 & 7, nlow = (u2 >> 3) & 7;
    int khigh = (u2 >> 6) & 1, nhigh = (u2 >> 7) & 7;
    int k8 = (klow + khigh * 8) * 8;
    int nn = nlow + nhigh * 8;
    unsigned short o8[8];
#pragma unroll
    for (int j = 0; j < 8; ++j) o8[j] = f2bf(t[(k8 + j) * 65 + nn]);
    *(uint4*)(Wt + (size_t)(n0 + nn) * K + k0 + k8) = *(uint4*)o8;
  }
}

// ---------------------------------------------------------------------------
// prep: gates (0..767, one wave per (t,gate)) + tcast(Wq,Wk,Wv,Wg)
// (768..2303) + castbf(x) (2304..2815).
// ---------------------------------------------------------------------------
__global__ __launch_bounds__(256) void prep_kernel(
    const float* __restrict__ x, const float* __restrict__ Wq,
    const float* __restrict__ Wk, const float* __restrict__ Wv,
    const float* __restrict__ Wg, unsigned short* __restrict__ xb16,
    unsigned short* __restrict__ WtAll,
    const float* __restrict__ Wa, const float* __restrict__ Wbeta,
    const float* __restrict__ Wal, const float* __restrict__ A_log,
    const float* __restrict__ dtb, const float* __restrict__ bbv,
    const float* __restrict__ balv, float* __restrict__ glog,
    float* __restrict__ beta, float* __restrict__ alpha) {
  __shared__ float smem[128 * 65];
  int b = blockIdx.x, tid = threadIdx.x;
  if (b < 768) {
    int w = tid >> 6, lane = tid & 63;
    int wid = b * 4 + w;             // 0..3071
    int t = wid / 3;                 // timestep
    int g = wid - t * 3;             // gate id
    const float* W = (g == 0) ? Wa : (g == 1) ? Wbeta : Wal;
    const float* xrow = x + (size_t)t * 2048;
    float s[16];
#pragma unroll
    for (int h = 0; h < 16; ++h) s[h] = 0.f;
#pragma unroll 4
    for (int j = 0; j < 32; ++j) {
      int k = j * 64 + lane;
      float xv = xrow[k];
      const float* wr = W + (size_t)k * 16;
      float4 w0 = *(const float4*)(wr + 0);
      float4 w1 = *(const float4*)(wr + 4);
      float4 w2 = *(const float4*)(wr + 8);
      float4 w3 = *(const float4*)(wr + 12);
      s[0]  = fmaf(xv, w0.x, s[0]);
      s[1]  = fmaf(xv, w0.y, s[1]);
      s[2]  = fmaf(xv, w0.z, s[2]);
      s[3]  = fmaf(xv, w0.w, s[3]);
      s[4]  = fmaf(xv, w1.x, s[4]);
      s[5]  = fmaf(xv, w1.y, s[5]);
      s[6]  = fmaf(xv, w1.z, s[6]);
      s[7]  = fmaf(xv, w1.w, s[7]);
      s[8]  = fmaf(xv, w2.x, s[8]);
      s[9]  = fmaf(xv, w2.y, s[9]);
      s[10] = fmaf(xv, w2.z, s[10]);
      s[11] = fmaf(xv, w2.w, s[11]);
      s[12] = fmaf(xv, w3.x, s[12]);
      s[13] = fmaf(xv, w3.y, s[13]);
      s[14] = fmaf(xv, w3.z, s[14]);
      s[15] = fmaf(xv, w3.w, s[15]);
    }
#pragma unroll
    for (int h = 0; h < 16; ++h) {
      float v = s[h];
#pragma unroll
      for (int off = 32; off; off >>= 1) v += __shfl_down(v, off);
      s[h] = v;
    }
    if (lane == 0) {
      if (g == 0) {
#pragma unroll
        for (int h = 0; h < 16; ++h) {
          float za = s[h] + dtb[h];
          float sp = fmaxf(za, 0.f) + log1pf(expf(-fabsf(za)));
          glog[t * 16 + h] = -expf(A_log[h]) * sp;
        }
      } else if (g == 1) {
#pragma unroll
        for (int h = 0; h < 16; ++h)
          beta[t * 16 + h] = 1.f / (1.f + expf(-(s[h] + bbv[h])));
      } else {
#pragma unroll
        for (int h = 0; h < 16; ++h)
          alpha[t * 16 + h] = 1.f / (1.f + expf(-(s[h] + balv[h])));
      }
    }
  } else if (b < 2304) {
    int r = b - 768;
    if (r < 512) {
      tcast_fat(Wq, WtAll, 2048, 2048, r & 31, r >> 5, tid, smem);
    } else if (r < 768) {
      int q = r - 512;
      tcast_fat(Wk, WtAll + (size_t)2048 * 2048, 2048, 1024, q & 15, q >> 4,
                tid, smem);
    } else if (r < 1024) {
      int q = r - 768;
      tcast_fat(Wv, WtAll + (size_t)3072 * 2048, 2048, 1024, q & 15, q >> 4,
                tid, smem);
    } else {
      int q = r - 1024;
      tcast_fat(Wg, WtAll + (size_t)4096 * 2048, 2048, 2048, q & 31, q >> 5,
                tid, smem);
    }
  } else {
    int i0 = (b - 2304) * 1024 + tid;
#pragma unroll
    for (int i = 0; i < 4; ++i) {
      int idx = i0 + i * 256;
      float4 v = ((const float4*)x)[idx];
      ushort4 u;
      u.x = f2bf(v.x); u.y = f2bf(v.y); u.z = f2bf(v.z); u.w = f2bf(v.w);
      ((ushort4*)xb16)[idx] = u;
    }
  }
}

// ---------------------------------------------------------------------------
// bf16 MFMA GEMM, m97 structure: C[M,N](f32) = A[M,K](bf16) @ Bt[N,K]^T.
// BM/BN template, BK=64.  256 thr = 4 waves (2x2 over BM/2 x BN/2).
// 128x64 @ 768 blocks (3/CU) is the empirical best for this 2-barrier
// structure at M=1024 (BN=96 @ 2/CU regressed; learn_hip tile-space).
// ---------------------------------------------------------------------------
template <int BM, int BN>
__global__ __launch_bounds__(256) void gemm_lds(
    const unsigned short* __restrict__ A, const unsigned short* __restrict__ Bt,
    float* __restrict__ C, int M, int N, int K) {
  __shared__ unsigned short As[BM * 64];
  __shared__ unsigned short Bs[BN * 64];
  constexpr int MT = BM / 32;
  constexpr int NT = BN / 32;
  constexpr int ACH = BM / 32;
  constexpr int BCH = BN / 32;
  int tid = threadIdx.x;
  int wave = tid >> 6, lane = tid & 63;
  int ln = lane & 15, hi = lane >> 4;
  int wm = wave & 1, wn = wave >> 1;
  int m0 = blockIdx.y * BM, n0 = blockIdx.x * BN;
  int lrow = lane >> 3, lcol = (lane & 7) * 8;

  floatx4 acc[MT][NT];
#pragma unroll
  for (int mt = 0; mt < MT; ++mt)
#pragma unroll
    for (int nt = 0; nt < NT; ++nt) acc[mt][nt] = (floatx4)(0.f);

  for (int k0 = 0; k0 < K; k0 += 64) {
#pragma unroll
    for (int i = 0; i < ACH; ++i) {
      int c = wave * ACH + i;
      gload16(A + (size_t)(m0 + c * 8 + lrow) * K + k0 + lcol, As + c * 512);
    }
#pragma unroll
    for (int i = 0; i < BCH; ++i) {
      int c = wave * BCH + i;
      gload16(Bt + (size_t)(n0 + c * 8 + lrow) * K + k0 + lcol, Bs + c * 512);
    }
    __syncthreads();
#pragma unroll
    for (int kb = 0; kb < 2; ++kb) {
      short8 a[MT], b[NT];
#pragma unroll
      for (int mt = 0; mt < MT; ++mt)
        a[mt] = *(const short8*)(As + (wm * (BM / 2) + mt * 16 + ln) * 64 +
                                 kb * 32 + hi * 8);
#pragma unroll
      for (int nt = 0; nt < NT; ++nt)
        b[nt] = *(const short8*)(Bs + (wn * (BN / 2) + nt * 16 + ln) * 64 +
                                 kb * 32 + hi * 8);
#pragma unroll
      for (int mt = 0; mt < MT; ++mt)
#pragma unroll
        for (int nt = 0; nt < NT; ++nt)
          acc[mt][nt] = __builtin_amdgcn_mfma_f32_16x16x32_bf16(
              a[mt], b[nt], acc[mt][nt], 0, 0, 0);
    }
    __syncthreads();
  }
#pragma unroll
  for (int mt = 0; mt < MT; ++mt)
#pragma unroll
    for (int nt = 0; nt < NT; ++nt) {
      int col = n0 + wn * (BN / 2) + nt * 16 + ln;
      int rowb = m0 + wm * (BM / 2) + mt * 16 + hi * 4;
#pragma unroll
      for (int r = 0; r < 4; ++r)
        C[(size_t)(rowb + r) * N + col] = acc[mt][nt][r];
    }
}

// ---------------------------------------------------------------------------
// Causal depthwise conv (K=4) + silu core.
// ---------------------------------------------------------------------------
__device__ __forceinline__ float conv_core(
    const float* __restrict__ xin, const float* __restrict__ w,
    int idx, int instride, int nch, float scale) {
  int t = idx / nch, ch = idx - t * nch;
  float acc = 0.f;
#pragma unroll
  for (int j = 0; j < 4; ++j) {
    int tt = t + j - 3;
    float xv = (tt >= 0) ? xin[(size_t)tt * instride + ch] : 0.f;
    acc = fmaf(xv, w[ch * 4 + j], acc);
  }
  return acc / (1.f + expf(-acc)) * scale;
}

// ---------------------------------------------------------------------------
// conv_all: q (bf16 out), k (f32+bf16 out), v (f32 out) + cumsum block.
// ---------------------------------------------------------------------------
__global__ __launch_bounds__(256) void conv_all(
    const float* __restrict__ xall, const float* __restrict__ convq,
    const float* __restrict__ convk, const float* __restrict__ convv,
    unsigned short* __restrict__ qs16, float* __restrict__ ks2,
    unsigned short* __restrict__ ks16, float* __restrict__ vs2,
    const float* __restrict__ glog, const float* __restrict__ beta,
    float* __restrict__ cs, float* __restrict__ wend) {
  int b = blockIdx.x, tid = threadIdx.x;
  if (b < 8192) {
    int idx = b * 256 + tid;
    qs16[idx] = f2bf(conv_core(xall, convq, idx, 6144, 2048,
                               0.08838834764831845f));
  } else if (b < 12288) {
    int idx = (b - 8192) * 256 + tid;
    float v = conv_core(xall + 2048, convk, idx, 6144, 1024, 1.0f);
    ks2[idx] = v;
    ks16[idx] = f2bf(v);
  } else if (b < 16384) {
    int idx = (b - 12288) * 256 + tid;
    vs2[idx] = conv_core(xall + 3072, convv, idx, 6144, 1024, 1.0f);
  } else {
    int idx = tid;
    int n = idx & 15;
    float acc = 0.f;
    for (int c = 0; c < CSZ; ++c) {
      acc += glog[(n * CSZ + c) * NHQ + (idx >> 4)];
      cs[idx * CSZ + c] = acc;
    }
    float G = acc;
    for (int c = 0; c < CSZ; ++c) {
      wend[idx * CSZ + c] =
          expf(G - cs[idx * CSZ + c]) * beta[(n * CSZ + c) * NHQ + (idx >> 4)];
    }
  }
}

// ---------------------------------------------------------------------------
// Gram increments per (h,n) via MFMA (blocks 0..255) + vtr (256..383).
// ---------------------------------------------------------------------------
__global__ __launch_bounds__(256) void dhb_kernel(
    const float* __restrict__ ks, const float* __restrict__ vs,
    const float* __restrict__ wend, float* __restrict__ dH,
    float* __restrict__ dB, unsigned short* __restrict__ vT16) {
  __shared__ uint4 smem4[4096];   // 64 KB
  int bid = blockIdx.x;
  int tid = threadIdx.x;

  if (bid >= 256) {
    // ---- vtr path ----
    float* t = (float*)smem4;
    int b = bid - 256;
    size_t gbase = ((size_t)(b >> 3)) * 65536 + ((size_t)(b & 7)) * 128;
#pragma unroll
    for (int g = 0; g < 8; ++g) {
      int i = tid + g * 256;
      int c = i >> 5, e4 = i & 31;
      float4 v = *(const float4*)(vs + gbase + (size_t)c * 1024 + e4 * 4);
      t[c * 132 + e4 * 4 + 0] = v.x;
      t[c * 132 + e4 * 4 + 1] = v.y;
      t[c * 132 + e4 * 4 + 2] = v.z;
      t[c * 132 + e4 * 4 + 3] = v.w;
    }
    __syncthreads();
    int e = tid >> 1, half = tid & 1;
    size_t obase = ((size_t)b << 13) + (size_t)e * 64 + half * 32;
#pragma unroll
    for (int cc = 0; cc < 8; ++cc) {
      int c0 = half * 32 + cc * 4;
      ushort4 u;
      u.x = f2bf(t[(c0 + 0) * 132 + e]);
      u.y = f2bf(t[(c0 + 1) * 132 + e]);
      u.z = f2bf(t[(c0 + 2) * 132 + e]);
      u.w = f2bf(t[(c0 + 3) * 132 + e]);
      *(ushort4*)(vT16 + obase + cc * 4) = u;
    }
    return;
  }

  // ---- dhb path ----
  unsigned short (*skF)[8192] = (unsigned short (*)[8192])smem4;
  unsigned short (*svF)[8192] =
      (unsigned short (*)[8192])((unsigned short*)smem4 + 16384);
  int h = bid >> 4, n = bid & 15;
  int hk = h >> 1;

#pragma unroll
  for (int p = 0; p < 4; ++p) {
    int t2 = tid + p * 256;
    int c0 = (t2 >> 7) << 3;
    int e = t2 & 127;
    int base = ((e >> 4) * 2 + (c0 >> 5)) * 512 +
               ((c0 & 31) >> 3) * 128 + (e & 15) * 8;
    unsigned short kh[8], kl[8], vh[8], vl[8];
#pragma unroll
    for (int j = 0; j < 8; ++j) {
      int c = c0 + j;
      float s = sqrtf(wend[bid * 64 + c]);
      size_t g = (size_t)(n * 64 + c) * 1024 + hk * 128 + e;
      float kf = s * ks[g];
      float vf = s * vs[g];
      unsigned short khh = f2bf(kf);
      kh[j] = khh; kl[j] = f2bf(kf - bf2f(khh));
      unsigned short vhh = f2bf(vf);
      vh[j] = vhh; vl[j] = f2bf(vf - bf2f(vhh));
    }
    *(uint4*)(&skF[0][base]) = *(uint4*)kh;
    *(uint4*)(&skF[1][base]) = *(uint4*)kl;
    *(uint4*)(&svF[0][base]) = *(uint4*)vh;
    *(uint4*)(&svF[1][base]) = *(uint4*)vl;
  }
  __syncthreads();

  int w = tid >> 6, lane = tid & 63;
  int ln = lane & 15, hi = lane >> 4;

  short8 ah[2][2], al[2][2];
#pragma unroll
  for (int mti = 0; mti < 2; ++mti) {
    int mt = w * 2 + mti;
#pragma unroll
    for (int ct = 0; ct < 2; ++ct) {
      ah[mti][ct] = *(const short8*)(&skF[0][((mt * 2 + ct) * 64 + lane) * 8]);
      al[mti][ct] = *(const short8*)(&skF[1][((mt * 2 + ct) * 64 + lane) * 8]);
    }
  }

  size_t gb = (size_t)bid << 14;
#pragma unroll
  for (int which = 0; which < 2; ++which) {
    const unsigned short (*BF)[8192] = which ? svF : skF;
    float* outp = which ? dB : dH;
#pragma unroll
    for (int nt = 0; nt < 8; ++nt) {
      floatx4 a0 = (floatx4)(0.f), a1 = (floatx4)(0.f);
#pragma unroll
      for (int ct = 0; ct < 2; ++ct) {
        short8 bh = *(const short8*)(&BF[0][((nt * 2 + ct) * 64 + lane) * 8]);
        short8 bl = *(const short8*)(&BF[1][((nt * 2 + ct) * 64 + lane) * 8]);
        a0 = __builtin_amdgcn_mfma_f32_16x16x32_bf16(ah[0][ct], bh, a0, 0, 0, 0);
        a0 = __builtin_amdgcn_mfma_f32_16x16x32_bf16(ah[0][ct], bl, a0, 0, 0, 0);
        a0 = __builtin_amdgcn_mfma_f32_16x16x32_bf16(al[0][ct], bh, a0, 0, 0, 0);
        a1 = __builtin_amdgcn_mfma_f32_16x16x32_bf16(ah[1][ct], bh, a1, 0, 0, 0);
        a1 = __builtin_amdgcn_mfma_f32_16x16x32_bf16(ah[1][ct], bl, a1, 0, 0, 0);
        a1 = __builtin_amdgcn_mfma_f32_16x16x32_bf16(al[1][ct], bh, a1, 0, 0, 0);
      }
      int e = nt * 16 + ln;
#pragma unroll
      for (int rg = 0; rg < 4; ++rg) {
        int d0 = (w * 2 + 0) * 16 + hi * 4 + rg;
        int d1 = (w * 2 + 1) * 16 + hi * 4 + rg;
        outp[gb + (size_t)d0 * 128 + e] = a0[rg];
        outp[gb + (size_t)d1 * 128 + e] = a1[rg];
      }
    }
  }
}

// ---------------------------------------------------------------------------
// Inter-chunk scan (in-place): store state at chunk start; A gets +ridge diag.
// ---------------------------------------------------------------------------
__global__ __launch_bounds__(256) void scan_kernel(
    float* __restrict__ dH, float* __restrict__ dB,
    const float* __restrict__ cs) {
  int idx = blockIdx.x * 256 + threadIdx.x;  // h*16384 + de
  int h = idx >> 14, de = idx & 16383;
  float Hs = 0.f, Bs = 0.f;
  bool diag = ((de % 129) == 0);
#pragma unroll 1
  for (int n = 0; n < NCH; ++n) {
    size_t off = ((size_t)(h * 16 + n) << 14) + de;
    float dh = dH[off], db = dB[off];
    dH[off] = diag ? (Hs + 0.02f) : Hs;
    dB[off] = Bs;
    float g = expf(cs[(h * 16 + n) * CSZ + (CSZ - 1)]);
    Hs = fmaf(g, Hs, dh);
    Bs = fmaf(g, Bs, db);
  }
}

// ---------------------------------------------------------------------------
// Chebyshev solve via MFMA, 8-way column split, 256 thr (4 waves).
// Single 2048-block launch: bm = bid&255, cb = bid>>8 (siblings of a matrix
// share bid%8 -> same XCD).  Round-11: the former afrag_kernel is FOLDED
// into the prologue -- each block reads its wave's A rows as f32 (L2-served,
// A = 4MB), applies the identical f2bf hi/lo split in registers, and
// computes the trace with the identical per-half 64-lane shfl tree and
// partial-sum order (bit-identical numerics).  Removes one kernel launch
// plus afrag's 32MB of traffic.
// ---------------------------------------------------------------------------
__global__ __launch_bounds__(256, 2) void cheb_kernel(
    const float* __restrict__ Aall, float* __restrict__ Ball) {
  int bid = blockIdx.x;
  int bm = bid & 255;               // matrix id (h*16+n)
  int cb = bid >> 8;                // column eighth
  const float* __restrict__ Ag = Aall + ((size_t)bm << 14);
  float* __restrict__ Bg = Ball + ((size_t)bm << 14);
  __shared__ unsigned short dT[2][2048];
  __shared__ float tsh[2];
  int tid = threadIdx.x;
  int w = tid >> 6, lane = tid & 63;
  int ln = lane & 15, q = lane >> 4;

  // trace partials: wave hf sums diag[hf*64 .. hf*64+64) via shfl tree
  // (identical order to the old afrag_kernel reduction).
  if (w < 2) {
    float tv = Ag[(size_t)(w * 64 + lane) * 129];
#pragma unroll
    for (int off = 32; off; off >>= 1) tv += __shfl_down(tv, off);
    if (lane == 0) tsh[w] = tv;
  }

  // A-frags from f32: frag (mt,kt) -> row m = w*32+mt*16+ln,
  // cols k = kt*32+q*8 .. +8; hi = f2bf(a), lo = f2bf(a - bf2f(hi)).
  short8 afr[2][4][2];
#pragma unroll
  for (int mt = 0; mt < 2; ++mt)
#pragma unroll
    for (int kt = 0; kt < 4; ++kt) {
      int m = w * 32 + mt * 16 + ln;
      int k = kt * 32 + q * 8;
      const float* ap = Ag + (size_t)m * 128 + k;
      float4 va = *(const float4*)(ap);
      float4 vb = *(const float4*)(ap + 4);
      float av[8] = {va.x, va.y, va.z, va.w, vb.x, vb.y, vb.z, vb.w};
      unsigned short hi8[8], lo8[8];
#pragma unroll
      for (int j = 0; j < 8; ++j) {
        unsigned short hv = f2bf(av[j]);
        hi8[j] = hv;
        lo8[j] = f2bf(av[j] - bf2f(hv));
      }
      afr[mt][kt][0] = *(short8*)hi8;
      afr[mt][kt][1] = *(short8*)lo8;
    }
  __syncthreads();
  float lmax = tsh[0] + tsh[1];

  const float lmin = 0.02f;
  float theta = 0.5f * (lmax + lmin);
  float delta = 0.5f * (lmax - lmin);
  float sigma1 = theta / delta;
  float rho = delta / theta;
  float invtheta = 1.f / theta;

  int wrB[2];
#pragma unroll
  for (int mt = 0; mt < 2; ++mt)
    wrB[mt] = w * 512 + (((mt * 2 + (q >> 1)) & 3) * 16 + ln) * 8 +
              ((q & 1) << 2);

  float xx[2][4], rr[2][4], dd[2][4];
#pragma unroll
  for (int mt = 0; mt < 2; ++mt) {
#pragma unroll
    for (int rg = 0; rg < 4; ++rg) {
      float b = Bg[(w * 32 + mt * 16 + q * 4 + rg) * 128 + cb * 16 + ln];
      rr[mt][rg] = b;
      xx[mt][rg] = 0.f;
      dd[mt][rg] = b * invtheta;
    }
    unsigned int p01 = cvtpk(dd[mt][0], dd[mt][1]);
    unsigned int p23 = cvtpk(dd[mt][2], dd[mt][3]);
    dd[mt][0] = __uint_as_float(p01 << 16);
    dd[mt][1] = __uint_as_float(p01 & 0xffff0000u);
    dd[mt][2] = __uint_as_float(p23 << 16);
    dd[mt][3] = __uint_as_float(p23 & 0xffff0000u);
    uint2 pk; pk.x = p01; pk.y = p23;
    *(uint2*)(&dT[0][wrB[mt]]) = pk;
  }
  __syncthreads();

#pragma unroll 1
  for (int it = 0; it < 30; ++it) {
    const unsigned short* dTr = dT[it & 1];
    unsigned short* dTw = dT[(it & 1) ^ 1];
    floatx4 a0 = (floatx4)(0.f), a1 = (floatx4)(0.f);
#pragma unroll
    for (int kt = 0; kt < 4; ++kt) {
      short8 df = *(const short8*)(dTr + kt * 512 + lane * 8);
      a0 = __builtin_amdgcn_mfma_f32_16x16x32_bf16(afr[0][kt][0], df, a0, 0, 0, 0);
      a0 = __builtin_amdgcn_mfma_f32_16x16x32_bf16(afr[0][kt][1], df, a0, 0, 0, 0);
      a1 = __builtin_amdgcn_mfma_f32_16x16x32_bf16(afr[1][kt][0], df, a1, 0, 0, 0);
      a1 = __builtin_amdgcn_mfma_f32_16x16x32_bf16(afr[1][kt][1], df, a1, 0, 0, 0);
    }
    float rho_n = 1.f / (2.f * sigma1 - rho);
    float c1s = rho_n * rho;
    float c2s = 2.f * rho_n / delta;
#pragma unroll
    for (int mt = 0; mt < 2; ++mt) {
      float dn[4];
#pragma unroll
      for (int rg = 0; rg < 4; ++rg) {
        xx[mt][rg] += dd[mt][rg];
        rr[mt][rg] -= mt ? a1[rg] : a0[rg];
        dn[rg] = fmaf(c1s, dd[mt][rg], c2s * rr[mt][rg]);
      }
      unsigned int p01 = cvtpk(dn[0], dn[1]);
      unsigned int p23 = cvtpk(dn[2], dn[3]);
      dd[mt][0] = __uint_as_float(p01 << 16);
      dd[mt][1] = __uint_as_float(p01 & 0xffff0000u);
      dd[mt][2] = __uint_as_float(p23 << 16);
      dd[mt][3] = __uint_as_float(p23 & 0xffff0000u);
      uint2 pk; pk.x = p01; pk.y = p23;
      *(uint2*)(&dTw[wrB[mt]]) = pk;
    }
    rho = rho_n;
    __syncthreads();
  }

  // X -> hi/lo bf16 B-operand fragments, chunk-swizzled in place over this
  // block's own B0 byte-set.
  unsigned short* Xf = (unsigned short*)Bg;
#pragma unroll
  for (int mt = 0; mt < 2; ++mt) {
    ushort4 h4, l4;
    unsigned short* hp = (unsigned short*)&h4;
    unsigned short* lp = (unsigned short*)&l4;
#pragma unroll
    for (int rg = 0; rg < 4; ++rg) {
      float xv = xx[mt][rg];
      unsigned short h = f2bf(xv);
      hp[rg] = h;
      lp[rg] = f2bf(xv - bf2f(h));
    }
    int lhi = wrB[mt];
    int llo = lhi + 2048;
    *(ushort4*)(Xf + ((lhi >> 5) << 8) + (cb << 5) + (lhi & 31)) = h4;
    *(ushort4*)(Xf + ((llo >> 5) << 8) + (cb << 5) + (llo & 31)) = l4;
  }
}

// ---------------------------------------------------------------------------
// Attention per (h,n), all-MFMA (blocks 0..255) + tcast(Wo) bn<16
// (blocks 256..511: bn=r&15, bk=r>>4, both in [0,16)).
// ---------------------------------------------------------------------------
__global__ __launch_bounds__(256) void attn_kernel(
    const unsigned short* __restrict__ q16, const unsigned short* __restrict__ k16,
    const unsigned short* __restrict__ vT16, const unsigned short* __restrict__ Xf,
    const float* __restrict__ vs, const float* __restrict__ cs,
    const float* __restrict__ beta, const float* __restrict__ alpha,
    float* __restrict__ o, const float* __restrict__ Wo,
    unsigned short* __restrict__ WtWo) {
  __shared__ __align__(16) float smem[11264];   // 45056 B union
  int tid = threadIdx.x;

  if (blockIdx.x >= 256) {
    int r = blockIdx.x - 256;        // 0..255
    int bn = r & 15, bk = r >> 4;    // bn in [0,16), bk in [0,16)
    tcast_fat(Wo, WtWo, 2048, 2048, bn, bk, tid, smem);
    return;
  }

  int bid = blockIdx.x;             // h*16+n
  int h = bid >> 4, n = bid & 15;
  int hk = h >> 1;
  unsigned short* qb = (unsigned short*)smem;          // 64*136
  unsigned short* kb = qb + 8704;                      // 64*136
  unsigned short* Sb = kb + 8704;                      // 64*72
  float* csL = smem + 11008;
  float* ecsL = csL + 64;
  float* betaL = ecsL + 64;
  float* alphaL = betaL + 64;
  int w = tid >> 6, lane = tid & 63;
  int ln = lane & 15, hi = lane >> 4;

  {
    size_t qgb = (((size_t)(n * 64)) * 16 + h) * 128;
    size_t kgb = (((size_t)(n * 64)) * 8 + hk) * 128;
#pragma unroll
    for (int g = 0; g < 4; ++g) {
      int i = tid + g * 256;
      int c = i >> 4, ch = i & 15;
      *(uint4*)(qb + c * 136 + ch * 8) =
          *(const uint4*)(q16 + qgb + (size_t)c * 2048 + ch * 8);
      *(uint4*)(kb + c * 136 + ch * 8) =
          *(const uint4*)(k16 + kgb + (size_t)c * 1024 + ch * 8);
    }
    if (tid < 64) {
      float cv = cs[bid * 64 + tid];
      csL[tid] = cv;
      ecsL[tid] = expf(cv);
      betaL[tid] = beta[(n * 64 + tid) * 16 + h];
      alphaL[tid] = alpha[(n * 64 + tid) * 16 + h];
    }
  }
  __syncthreads();

  short8 aq[4];
#pragma unroll
  for (int dt = 0; dt < 4; ++dt)
    aq[dt] = *(const short8*)(qb + (w * 16 + ln) * 136 + dt * 32 + hi * 8);

  // phase 1: o_inter = q @ X (hi+lo planes), then scale rows by exp(cs)
  const unsigned short* Xb = Xf + ((size_t)bid << 15);
  floatx4 acc[8];
#pragma unroll
  for (int et = 0; et < 8; ++et) {
    floatx4 a = (floatx4)(0.f);
#pragma unroll
    for (int dt = 0; dt < 4; ++dt) {
      int base = ((dt * 16 + (lane >> 2)) << 8) + (et << 5) + ((lane & 3) << 3);
      short8 xh = *(const short8*)(Xb + base);
      short8 xl = *(const short8*)(Xb + base + 16384);
      a = __builtin_amdgcn_mfma_f32_16x16x32_bf16(aq[dt], xh, a, 0, 0, 0);
      a = __builtin_amdgcn_mfma_f32_16x16x32_bf16(aq[dt], xl, a, 0, 0, 0);
    }
    acc[et] = a;
  }
#pragma unroll
  for (int et = 0; et < 8; ++et)
#pragma unroll
    for (int rg = 0; rg < 4; ++rg)
      acc[et][rg] *= ecsL[w * 16 + hi * 4 + rg];

  // phase 2: gated causal scores -> Sb (bf16), wave-local rows
#pragma unroll
  for (int jt = 0; jt < 4; ++jt) {
    if (jt <= w) {
      floatx4 s = (floatx4)(0.f);
#pragma unroll
      for (int dt = 0; dt < 4; ++dt) {
        short8 bk = *(const short8*)(kb + (jt * 16 + ln) * 136 + dt * 32 + hi * 8);
        s = __builtin_amdgcn_mfma_f32_16x16x32_bf16(aq[dt], bk, s, 0, 0, 0);
      }
      int j = jt * 16 + ln;
      float csj = csL[j], bj = betaL[j];
#pragma unroll
      for (int rg = 0; rg < 4; ++rg) {
        int c = w * 16 + hi * 4 + rg;
        float v = (j <= c) ? s[rg] * expf(csL[c] - csj) * bj : 0.f;
        Sb[c * 72 + j] = f2bf(v);
      }
    } else {
#pragma unroll
      for (int rg = 0; rg < 4; ++rg)
        Sb[(w * 16 + hi * 4 + rg) * 72 + jt * 16 + ln] = 0;
    }
  }

  // phase 3: O += S @ v
  const unsigned short* vTb = vT16 + ((size_t)(n * 8 + hk) << 13);
#pragma unroll
  for (int et = 0; et < 8; ++et) {
#pragma unroll
    for (int kt = 0; kt < 2; ++kt) {
      short8 as = *(const short8*)(Sb + (w * 16 + ln) * 72 + kt * 32 + hi * 8);
      short8 bv = *(const short8*)(vTb + (et * 16 + ln) * 64 + kt * 32 + hi * 8);
      acc[et] = __builtin_amdgcn_mfma_f32_16x16x32_bf16(as, bv, acc[et], 0, 0, 0);
    }
  }

  // epilogue: + alpha*v, store
#pragma unroll
  for (int et = 0; et < 8; ++et) {
#pragma unroll
    for (int rg = 0; rg < 4; ++rg) {
      int c = w * 16 + hi * 4 + rg, e = et * 16 + ln;
      size_t oaddr = (((size_t)(n * 64 + c)) * 16 + h) * 128 + e;
      size_t vaddr = (((size_t)(n * 64 + c)) * 8 + hk) * 128 + e;
      o[oaddr] = acc[et][rg] + alphaL[c] * vs[vaddr];
    }
  }
}

// ---------------------------------------------------------------------------
// rmso: tcast(Wo) bn>=16 (blocks 0..255) + gated RMSNorm (256..4351).
// ---------------------------------------------------------------------------
__global__ __launch_bounds__(256) void rmso_kernel(
    const float* __restrict__ o, const float* __restrict__ xall,
    const float* __restrict__ norm_w, unsigned short* __restrict__ onorm,
    const float* __restrict__ Wo, unsigned short* __restrict__ WtWo) {
  __shared__ float t[128 * 65];
  int b = blockIdx.x, tid = threadIdx.x;
  if (b < 256) {
    int bn = 16 + (b & 15), bk = b >> 4;   // bn in [16,32), bk in [0,16)
    tcast_fat(Wo, WtWo, 2048, 2048, bn, bk, tid, t);
  } else {
    int bb = b - 256;
    int wave = tid >> 6, lane = tid & 63;
    int row = bb * 4 + wave;         // t*16 + h
    size_t base = (size_t)row * HDIM;
    size_t gbase = (size_t)(row >> 4) * 6144 + 4096 + (size_t)(row & 15) * HDIM;
    float v0 = o[base + lane], v1 = o[base + lane + 64];
    float ss = fmaf(v0, v0, v1 * v1);
#pragma unroll
    for (int off = 32; off; off >>= 1) ss += __shfl_down(ss, off);
    ss = __shfl(ss, 0);
    float rinv = rsqrtf(ss * (1.f / 128.f) + 1e-6f);
    float g0 = xall[gbase + lane], g1 = xall[gbase + lane + 64];
    float s0 = g0 / (1.f + expf(-g0));
    float s1 = g1 / (1.f + expf(-g1));
    onorm[base + lane]      = f2bf(v0 * rinv * norm_w[lane] * s0);
    onorm[base + lane + 64] = f2bf(v1 * rinv * norm_w[lane + 64] * s1);
  }
}

// ---------------------------------------------------------------------------
extern "C" void kernel_launch(void* const* d_in, const int* in_sizes, int n_in,
                              void* d_out, int out_size, void* d_ws,
                              size_t ws_size, hipStream_t stream) {
  (void)in_sizes; (void)n_in; (void)out_size; (void)ws_size;
  const float* x      = (const float*)d_in[0];
  const float* Wq     = (const float*)d_in[1];
  const float* Wk     = (const float*)d_in[2];
  const float* Wv     = (const float*)d_in[3];
  const float* convq  = (const float*)d_in[4];
  const float* convk  = (const float*)d_in[5];
  const float* convv  = (const float*)d_in[6];
  const float* Wa     = (const float*)d_in[7];
  const float* A_log  = (const float*)d_in[8];
  const float* dtb    = (const float*)d_in[9];
  const float* Wb     = (const float*)d_in[10];
  const float* bbv    = (const float*)d_in[11];
  const float* Wal    = (const float*)d_in[12];
  const float* balv   = (const float*)d_in[13];
  const float* Wg     = (const float*)d_in[14];
  const float* norm_w = (const float*)d_in[15];
  const float* Wo     = (const float*)d_in[16];
  float* out = (float*)d_out;

  // workspace layout (float slots), ~88.5 MB total
  float* p = (float*)d_ws;
  float* xall  = p; p += 6291456;   // [L][6144]: q|k|v|g projections
  float* qslot = p; p += 2097152;   // carved: qs16 | ks16 | vT16 (bf16)
  float* ks2   = p; p += 1048576;   // + vs2: reused as WtWo (bf16) post-attn
  float* vs2   = p; p += 1048576;
  float* ob    = p; p += 2097152;
  float* glog  = p; p += 16384;
  float* beta  = p; p += 16384;
  float* alpha = p; p += 16384;
  float* csb   = p; p += 16384;
  float* wend  = p; p += 16384;
  float* traces= p; p += 16384;     // unused (trace folded into cheb)
  float* dHn   = p; p += 4194304;   // -> A (f32, read directly by cheb)
  float* dBn   = p; p += 4194304;   // -> B0 -> X-frags (bf16 hi/lo) in place
  unsigned short* xb16 = (unsigned short*)p; p += 1048576;
  (void)traces;

  unsigned short* qs16 = (unsigned short*)qslot;     // 1024*2048
  unsigned short* ks16 = qs16 + 2097152;             // 1024*1024
  unsigned short* vT16 = ks16 + 1048576;             // 128*128*64
  unsigned short* WtAll = (unsigned short*)dHn;      // 24 MB over dHn+dBn
  unsigned short* WtWo  = (unsigned short*)ks2;      // 8 MB over ks2+vs2
  unsigned short* onorm16 = xb16;                    // free after projections

  dim3 blk(256);
  // gates (wave per (t,g), coalesced) + fat tcast q|k|v|g + castbf(x)
  prep_kernel<<<2816, blk, 0, stream>>>(x, Wq, Wk, Wv, Wg, xb16, WtAll,
                                        Wa, Wb, Wal, A_log, dtb, bbv, balv,
                                        glog, beta, alpha);
  gemm_lds<128, 64><<<dim3(96, 8), blk, 0, stream>>>(xb16, WtAll, xall,
                                                     1024, 6144, 2048);
  // causal conv + silu (q scaled by HD^-0.5) + cumsum/w_end tail block
  conv_all<<<16385, blk, 0, stream>>>(xall, convq, convk, convv,
                                      qs16, ks2, ks16, vs2,
                                      glog, beta, csb, wend);
  // gram increments (MFMA) + v-transpose blocks, scan, Chebyshev (with
  // in-prologue A-frag conversion + trace; afrag kernel eliminated)
  dhb_kernel<<<384, blk, 0, stream>>>(ks2, vs2, wend, dHn, dBn, vT16);
  scan_kernel<<<1024, blk, 0, stream>>>(dHn, dBn, csb);
  cheb_kernel<<<2048, blk, 0, stream>>>(dHn, dBn);
  // attention (all-MFMA) + tcast(Wo) rows < 1024 (ks2 region, dead)
  attn_kernel<<<512, blk, 0, stream>>>(qs16, ks16, vT16, (unsigned short*)dBn,
                                       vs2, csb, beta, alpha, ob, Wo, WtWo);
  // tcast(Wo) rows >= 1024 (vs2 region, dead after attn) + RMSNorm
  rmso_kernel<<<4352, blk, 0, stream>>>(ob, xall, norm_w, onorm16, Wo, WtWo);
  gemm_lds<64, 64><<<dim3(32, 16), blk, 0, stream>>>(onorm16, WtWo, out,
                                                     1024, 2048, 2048);
}

// Round 12
// 371.951 us; speedup vs baseline: 1.1426x; 1.0268x over previous
//
#include <hip/hip_runtime.h>
#include <math.h>

// GatedKalmaNet: B=1, L=1024, D=2048, HQ=16, HK=8, HD=128, CONV=4, CHUNK=64,
// Nc=16, NUM_ITER=30, RIDGE=0.02, EPS=1e-6.

#define LSEQ 1024
#define DM   2048
#define NHQ  16
#define NHK  8
#define HDIM 128
#define NCH  16
#define CSZ  64

typedef __attribute__((ext_vector_type(8))) short short8;
typedef __attribute__((ext_vector_type(4))) float floatx4;

// f32 -> bf16 RNE
__device__ __forceinline__ unsigned short f2bf(float f) {
  unsigned int u = __float_as_uint(f);
  u += 0x7fffu + ((u >> 16) & 1u);
  return (unsigned short)(u >> 16);
}
__device__ __forceinline__ float bf2f(unsigned short u) {
  return __uint_as_float(((unsigned int)u) << 16);
}

// packed f32x2 -> bf16x2 (RNE), lo half = first operand
__device__ __forceinline__ unsigned int cvtpk(float a, float b) {
  unsigned int r;
  asm("v_cvt_pk_bf16_f32 %0, %1, %2" : "=v"(r) : "v"(a), "v"(b));
  return r;
}

// async global->LDS, 16B per lane (wave-uniform LDS base + lane*16)
__device__ __forceinline__ void gload16(const unsigned short* g,
                                        unsigned short* l) {
  __builtin_amdgcn_global_load_lds(
      (const __attribute__((address_space(1))) unsigned int*)g,
      (__attribute__((address_space(3))) unsigned int*)l, 16, 0, 0);
}

// ---------------------------------------------------------------------------
// Fat transpose-cast: W[K][N] f32 -> Wt[N][K] bf16, one 128(k) x 64(n) tile.
// Valid tile ranges for 2048x2048: bk in [0,16), bn in [0,32).
// ---------------------------------------------------------------------------
__device__ __forceinline__ void tcast_fat(
    const float* __restrict__ W, unsigned short* __restrict__ Wt,
    int K, int N, int bn, int bk, int tid, float* __restrict__ t) {
  int k0 = bk * 128, n0 = bn * 64;
#pragma unroll
  for (int i = 0; i < 8; ++i) {
    int u = tid + i * 256;
    int r = u >> 4, c4 = u & 15;
    float4 v = *(const float4*)(W + (size_t)(k0 + r) * N + n0 + c4 * 4);
    float* dst = t + r * 65 + c4 * 4;
    dst[0] = v.x; dst[1] = v.y; dst[2] = v.z; dst[3] = v.w;
  }
  __syncthreads();
#pragma unroll
  for (int i = 0; i < 4; ++i) {
    int u2 = tid + i * 256;
    int klow = u2 & 7, nlow = (u2 >> 3) & 7;
    int khigh = (u2 >> 6) & 1, nhigh = (u2 >> 7) & 7;
    int k8 = (klow + khigh * 8) * 8;
    int nn = nlow + nhigh * 8;
    unsigned short o8[8];
#pragma unroll
    for (int j = 0; j < 8; ++j) o8[j] = f2bf(t[(k8 + j) * 65 + nn]);
    *(uint4*)(Wt + (size_t)(n0 + nn) * K + k0 + k8) = *(uint4*)o8;
  }
}

// ---------------------------------------------------------------------------
// prep: gates (0..767, one wave per (t,gate)) + tcast(Wq,Wk,Wv,Wg)
// (768..2303) + castbf(x) (2304..2815).
// ---------------------------------------------------------------------------
__global__ __launch_bounds__(256) void prep_kernel(
    const float* __restrict__ x, const float* __restrict__ Wq,
    const float* __restrict__ Wk, const float* __restrict__ Wv,
    const float* __restrict__ Wg, unsigned short* __restrict__ xb16,
    unsigned short* __restrict__ WtAll,
    const float* __restrict__ Wa, const float* __restrict__ Wbeta,
    const float* __restrict__ Wal, const float* __restrict__ A_log,
    const float* __restrict__ dtb, const float* __restrict__ bbv,
    const float* __restrict__ balv, float* __restrict__ glog,
    float* __restrict__ beta, float* __restrict__ alpha) {
  __shared__ float smem[128 * 65];
  int b = blockIdx.x, tid = threadIdx.x;
  if (b < 768) {
    int w = tid >> 6, lane = tid & 63;
    int wid = b * 4 + w;             // 0..3071
    int t = wid / 3;                 // timestep
    int g = wid - t * 3;             // gate id
    const float* W = (g == 0) ? Wa : (g == 1) ? Wbeta : Wal;
    const float* xrow = x + (size_t)t * 2048;
    float s[16];
#pragma unroll
    for (int h = 0; h < 16; ++h) s[h] = 0.f;
#pragma unroll 4
    for (int j = 0; j < 32; ++j) {
      int k = j * 64 + lane;
      float xv = xrow[k];
      const float* wr = W + (size_t)k * 16;
      float4 w0 = *(const float4*)(wr + 0);
      float4 w1 = *(const float4*)(wr + 4);
      float4 w2 = *(const float4*)(wr + 8);
      float4 w3 = *(const float4*)(wr + 12);
      s[0]  = fmaf(xv, w0.x, s[0]);
      s[1]  = fmaf(xv, w0.y, s[1]);
      s[2]  = fmaf(xv, w0.z, s[2]);
      s[3]  = fmaf(xv, w0.w, s[3]);
      s[4]  = fmaf(xv, w1.x, s[4]);
      s[5]  = fmaf(xv, w1.y, s[5]);
      s[6]  = fmaf(xv, w1.z, s[6]);
      s[7]  = fmaf(xv, w1.w, s[7]);
      s[8]  = fmaf(xv, w2.x, s[8]);
      s[9]  = fmaf(xv, w2.y, s[9]);
      s[10] = fmaf(xv, w2.z, s[10]);
      s[11] = fmaf(xv, w2.w, s[11]);
      s[12] = fmaf(xv, w3.x, s[12]);
      s[13] = fmaf(xv, w3.y, s[13]);
      s[14] = fmaf(xv, w3.z, s[14]);
      s[15] = fmaf(xv, w3.w, s[15]);
    }
#pragma unroll
    for (int h = 0; h < 16; ++h) {
      float v = s[h];
#pragma unroll
      for (int off = 32; off; off >>= 1) v += __shfl_down(v, off);
      s[h] = v;
    }
    if (lane == 0) {
      if (g == 0) {
#pragma unroll
        for (int h = 0; h < 16; ++h) {
          float za = s[h] + dtb[h];
          float sp = fmaxf(za, 0.f) + log1pf(expf(-fabsf(za)));
          glog[t * 16 + h] = -expf(A_log[h]) * sp;
        }
      } else if (g == 1) {
#pragma unroll
        for (int h = 0; h < 16; ++h)
          beta[t * 16 + h] = 1.f / (1.f + expf(-(s[h] + bbv[h])));
      } else {
#pragma unroll
        for (int h = 0; h < 16; ++h)
          alpha[t * 16 + h] = 1.f / (1.f + expf(-(s[h] + balv[h])));
      }
    }
  } else if (b < 2304) {
    int r = b - 768;
    if (r < 512) {
      tcast_fat(Wq, WtAll, 2048, 2048, r & 31, r >> 5, tid, smem);
    } else if (r < 768) {
      int q = r - 512;
      tcast_fat(Wk, WtAll + (size_t)2048 * 2048, 2048, 1024, q & 15, q >> 4,
                tid, smem);
    } else if (r < 1024) {
      int q = r - 768;
      tcast_fat(Wv, WtAll + (size_t)3072 * 2048, 2048, 1024, q & 15, q >> 4,
                tid, smem);
    } else {
      int q = r - 1024;
      tcast_fat(Wg, WtAll + (size_t)4096 * 2048, 2048, 2048, q & 31, q >> 5,
                tid, smem);
    }
  } else {
    int i0 = (b - 2304) * 1024 + tid;
#pragma unroll
    for (int i = 0; i < 4; ++i) {
      int idx = i0 + i * 256;
      float4 v = ((const float4*)x)[idx];
      ushort4 u;
      u.x = f2bf(v.x); u.y = f2bf(v.y); u.z = f2bf(v.z); u.w = f2bf(v.w);
      ((ushort4*)xb16)[idx] = u;
    }
  }
}

// ---------------------------------------------------------------------------
// bf16 MFMA GEMM, m97 structure: C[M,N](f32) = A[M,K](bf16) @ Bt[N,K]^T.
// 128x64 @ 768 blocks (3/CU) is the empirical best at M=1024.
// ---------------------------------------------------------------------------
template <int BM, int BN>
__global__ __launch_bounds__(256) void gemm_lds(
    const unsigned short* __restrict__ A, const unsigned short* __restrict__ Bt,
    float* __restrict__ C, int M, int N, int K) {
  __shared__ unsigned short As[BM * 64];
  __shared__ unsigned short Bs[BN * 64];
  constexpr int MT = BM / 32;
  constexpr int NT = BN / 32;
  constexpr int ACH = BM / 32;
  constexpr int BCH = BN / 32;
  int tid = threadIdx.x;
  int wave = tid >> 6, lane = tid & 63;
  int ln = lane & 15, hi = lane >> 4;
  int wm = wave & 1, wn = wave >> 1;
  int m0 = blockIdx.y * BM, n0 = blockIdx.x * BN;
  int lrow = lane >> 3, lcol = (lane & 7) * 8;

  floatx4 acc[MT][NT];
#pragma unroll
  for (int mt = 0; mt < MT; ++mt)
#pragma unroll
    for (int nt = 0; nt < NT; ++nt) acc[mt][nt] = (floatx4)(0.f);

  for (int k0 = 0; k0 < K; k0 += 64) {
#pragma unroll
    for (int i = 0; i < ACH; ++i) {
      int c = wave * ACH + i;
      gload16(A + (size_t)(m0 + c * 8 + lrow) * K + k0 + lcol, As + c * 512);
    }
#pragma unroll
    for (int i = 0; i < BCH; ++i) {
      int c = wave * BCH + i;
      gload16(Bt + (size_t)(n0 + c * 8 + lrow) * K + k0 + lcol, Bs + c * 512);
    }
    __syncthreads();
#pragma unroll
    for (int kb = 0; kb < 2; ++kb) {
      short8 a[MT], b[NT];
#pragma unroll
      for (int mt = 0; mt < MT; ++mt)
        a[mt] = *(const short8*)(As + (wm * (BM / 2) + mt * 16 + ln) * 64 +
                                 kb * 32 + hi * 8);
#pragma unroll
      for (int nt = 0; nt < NT; ++nt)
        b[nt] = *(const short8*)(Bs + (wn * (BN / 2) + nt * 16 + ln) * 64 +
                                 kb * 32 + hi * 8);
#pragma unroll
      for (int mt = 0; mt < MT; ++mt)
#pragma unroll
        for (int nt = 0; nt < NT; ++nt)
          acc[mt][nt] = __builtin_amdgcn_mfma_f32_16x16x32_bf16(
              a[mt], b[nt], acc[mt][nt], 0, 0, 0);
    }
    __syncthreads();
  }
#pragma unroll
  for (int mt = 0; mt < MT; ++mt)
#pragma unroll
    for (int nt = 0; nt < NT; ++nt) {
      int col = n0 + wn * (BN / 2) + nt * 16 + ln;
      int rowb = m0 + wm * (BM / 2) + mt * 16 + hi * 4;
#pragma unroll
      for (int r = 0; r < 4; ++r)
        C[(size_t)(rowb + r) * N + col] = acc[mt][nt][r];
    }
}

// ---------------------------------------------------------------------------
// Causal depthwise conv (K=4) + silu core.
// ---------------------------------------------------------------------------
__device__ __forceinline__ float conv_core(
    const float* __restrict__ xin, const float* __restrict__ w,
    int idx, int instride, int nch, float scale) {
  int t = idx / nch, ch = idx - t * nch;
  float acc = 0.f;
#pragma unroll
  for (int j = 0; j < 4; ++j) {
    int tt = t + j - 3;
    float xv = (tt >= 0) ? xin[(size_t)tt * instride + ch] : 0.f;
    acc = fmaf(xv, w[ch * 4 + j], acc);
  }
  return acc / (1.f + expf(-acc)) * scale;
}

// ---------------------------------------------------------------------------
// conv_all: q (bf16 out), k (f32+bf16 out), v (f32 out) + cumsum block.
// ---------------------------------------------------------------------------
__global__ __launch_bounds__(256) void conv_all(
    const float* __restrict__ xall, const float* __restrict__ convq,
    const float* __restrict__ convk, const float* __restrict__ convv,
    unsigned short* __restrict__ qs16, float* __restrict__ ks2,
    unsigned short* __restrict__ ks16, float* __restrict__ vs2,
    const float* __restrict__ glog, const float* __restrict__ beta,
    float* __restrict__ cs, float* __restrict__ wend) {
  int b = blockIdx.x, tid = threadIdx.x;
  if (b < 8192) {
    int idx = b * 256 + tid;
    qs16[idx] = f2bf(conv_core(xall, convq, idx, 6144, 2048,
                               0.08838834764831845f));
  } else if (b < 12288) {
    int idx = (b - 8192) * 256 + tid;
    float v = conv_core(xall + 2048, convk, idx, 6144, 1024, 1.0f);
    ks2[idx] = v;
    ks16[idx] = f2bf(v);
  } else if (b < 16384) {
    int idx = (b - 12288) * 256 + tid;
    vs2[idx] = conv_core(xall + 3072, convv, idx, 6144, 1024, 1.0f);
  } else {
    int idx = tid;
    int n = idx & 15;
    float acc = 0.f;
    for (int c = 0; c < CSZ; ++c) {
      acc += glog[(n * CSZ + c) * NHQ + (idx >> 4)];
      cs[idx * CSZ + c] = acc;
    }
    float G = acc;
    for (int c = 0; c < CSZ; ++c) {
      wend[idx * CSZ + c] =
          expf(G - cs[idx * CSZ + c]) * beta[(n * CSZ + c) * NHQ + (idx >> 4)];
    }
  }
}

// ---------------------------------------------------------------------------
// Gram increments per (h,n) via MFMA (blocks 0..255) + vtr (256..383).
// ---------------------------------------------------------------------------
__global__ __launch_bounds__(256) void dhb_kernel(
    const float* __restrict__ ks, const float* __restrict__ vs,
    const float* __restrict__ wend, float* __restrict__ dH,
    float* __restrict__ dB, unsigned short* __restrict__ vT16) {
  __shared__ uint4 smem4[4096];   // 64 KB
  int bid = blockIdx.x;
  int tid = threadIdx.x;

  if (bid >= 256) {
    // ---- vtr path ----
    float* t = (float*)smem4;
    int b = bid - 256;
    size_t gbase = ((size_t)(b >> 3)) * 65536 + ((size_t)(b & 7)) * 128;
#pragma unroll
    for (int g = 0; g < 8; ++g) {
      int i = tid + g * 256;
      int c = i >> 5, e4 = i & 31;
      float4 v = *(const float4*)(vs + gbase + (size_t)c * 1024 + e4 * 4);
      t[c * 132 + e4 * 4 + 0] = v.x;
      t[c * 132 + e4 * 4 + 1] = v.y;
      t[c * 132 + e4 * 4 + 2] = v.z;
      t[c * 132 + e4 * 4 + 3] = v.w;
    }
    __syncthreads();
    int e = tid >> 1, half = tid & 1;
    size_t obase = ((size_t)b << 13) + (size_t)e * 64 + half * 32;
#pragma unroll
    for (int cc = 0; cc < 8; ++cc) {
      int c0 = half * 32 + cc * 4;
      ushort4 u;
      u.x = f2bf(t[(c0 + 0) * 132 + e]);
      u.y = f2bf(t[(c0 + 1) * 132 + e]);
      u.z = f2bf(t[(c0 + 2) * 132 + e]);
      u.w = f2bf(t[(c0 + 3) * 132 + e]);
      *(ushort4*)(vT16 + obase + cc * 4) = u;
    }
    return;
  }

  // ---- dhb path ----
  unsigned short (*skF)[8192] = (unsigned short (*)[8192])smem4;
  unsigned short (*svF)[8192] =
      (unsigned short (*)[8192])((unsigned short*)smem4 + 16384);
  int h = bid >> 4, n = bid & 15;
  int hk = h >> 1;

#pragma unroll
  for (int p = 0; p < 4; ++p) {
    int t2 = tid + p * 256;
    int c0 = (t2 >> 7) << 3;
    int e = t2 & 127;
    int base = ((e >> 4) * 2 + (c0 >> 5)) * 512 +
               ((c0 & 31) >> 3) * 128 + (e & 15) * 8;
    unsigned short kh[8], kl[8], vh[8], vl[8];
#pragma unroll
    for (int j = 0; j < 8; ++j) {
      int c = c0 + j;
      float s = sqrtf(wend[bid * 64 + c]);
      size_t g = (size_t)(n * 64 + c) * 1024 + hk * 128 + e;
      float kf = s * ks[g];
      float vf = s * vs[g];
      unsigned short khh = f2bf(kf);
      kh[j] = khh; kl[j] = f2bf(kf - bf2f(khh));
      unsigned short vhh = f2bf(vf);
      vh[j] = vhh; vl[j] = f2bf(vf - bf2f(vhh));
    }
    *(uint4*)(&skF[0][base]) = *(uint4*)kh;
    *(uint4*)(&skF[1][base]) = *(uint4*)kl;
    *(uint4*)(&svF[0][base]) = *(uint4*)vh;
    *(uint4*)(&svF[1][base]) = *(uint4*)vl;
  }
  __syncthreads();

  int w = tid >> 6, lane = tid & 63;
  int ln = lane & 15, hi = lane >> 4;

  short8 ah[2][2], al[2][2];
#pragma unroll
  for (int mti = 0; mti < 2; ++mti) {
    int mt = w * 2 + mti;
#pragma unroll
    for (int ct = 0; ct < 2; ++ct) {
      ah[mti][ct] = *(const short8*)(&skF[0][((mt * 2 + ct) * 64 + lane) * 8]);
      al[mti][ct] = *(const short8*)(&skF[1][((mt * 2 + ct) * 64 + lane) * 8]);
    }
  }

  size_t gb = (size_t)bid << 14;
#pragma unroll
  for (int which = 0; which < 2; ++which) {
    const unsigned short (*BF)[8192] = which ? svF : skF;
    float* outp = which ? dB : dH;
#pragma unroll
    for (int nt = 0; nt < 8; ++nt) {
      floatx4 a0 = (floatx4)(0.f), a1 = (floatx4)(0.f);
#pragma unroll
      for (int ct = 0; ct < 2; ++ct) {
        short8 bh = *(const short8*)(&BF[0][((nt * 2 + ct) * 64 + lane) * 8]);
        short8 bl = *(const short8*)(&BF[1][((nt * 2 + ct) * 64 + lane) * 8]);
        a0 = __builtin_amdgcn_mfma_f32_16x16x32_bf16(ah[0][ct], bh, a0, 0, 0, 0);
        a0 = __builtin_amdgcn_mfma_f32_16x16x32_bf16(ah[0][ct], bl, a0, 0, 0, 0);
        a0 = __builtin_amdgcn_mfma_f32_16x16x32_bf16(al[0][ct], bh, a0, 0, 0, 0);
        a1 = __builtin_amdgcn_mfma_f32_16x16x32_bf16(ah[1][ct], bh, a1, 0, 0, 0);
        a1 = __builtin_amdgcn_mfma_f32_16x16x32_bf16(ah[1][ct], bl, a1, 0, 0, 0);
        a1 = __builtin_amdgcn_mfma_f32_16x16x32_bf16(al[1][ct], bh, a1, 0, 0, 0);
      }
      int e = nt * 16 + ln;
#pragma unroll
      for (int rg = 0; rg < 4; ++rg) {
        int d0 = (w * 2 + 0) * 16 + hi * 4 + rg;
        int d1 = (w * 2 + 1) * 16 + hi * 4 + rg;
        outp[gb + (size_t)d0 * 128 + e] = a0[rg];
        outp[gb + (size_t)d1 * 128 + e] = a1[rg];
      }
    }
  }
}

// ---------------------------------------------------------------------------
// Inter-chunk scan (in-place): store state at chunk start; A gets +ridge diag.
// ---------------------------------------------------------------------------
__global__ __launch_bounds__(256) void scan_kernel(
    float* __restrict__ dH, float* __restrict__ dB,
    const float* __restrict__ cs) {
  int idx = blockIdx.x * 256 + threadIdx.x;  // h*16384 + de
  int h = idx >> 14, de = idx & 16383;
  float Hs = 0.f, Bs = 0.f;
  bool diag = ((de % 129) == 0);
#pragma unroll 1
  for (int n = 0; n < NCH; ++n) {
    size_t off = ((size_t)(h * 16 + n) << 14) + de;
    float dh = dH[off], db = dB[off];
    dH[off] = diag ? (Hs + 0.02f) : Hs;
    dB[off] = Bs;
    float g = expf(cs[(h * 16 + n) * CSZ + (CSZ - 1)]);
    Hs = fmaf(g, Hs, dh);
    Bs = fmaf(g, Bs, db);
  }
}

// ---------------------------------------------------------------------------
// Chebyshev solve via MFMA, 4-way column split, 256 thr (4 waves).
// Grid 1024: bm = bid&255, cb = bid>>8 in [0,4) (32-col strip; siblings of
// a matrix share bid%8 -> same XCD).  Round-12: 4-way (vs 8-way) halves the
// per-matrix A-conversion redundancy (4 sibling blocks, 2 grid rounds vs 4)
// and gives each wave 2 independent n-tiles (32 MFMA/iter, 4 indep 8-deep
// chains).  A-conversion uses v_cvt_pk_bf16_f32 (RNE, bit-identical to
// f2bf) -- ~3 VALU/elem vs ~8.  Trace via identical per-half shfl tree.
// X in-place over this block's own B0 byte-set: hi at short idx
// (l>>6)*256 + cb*64 + (l&63) (rows 0..63), lo at +16384 (rows 64..127).
// ---------------------------------------------------------------------------
__global__ __launch_bounds__(256, 2) void cheb_kernel(
    const float* __restrict__ Aall, float* __restrict__ Ball) {
  int bid = blockIdx.x;
  int bm = bid & 255;               // matrix id (h*16+n)
  int cb = bid >> 8;                // column quarter [0,4)
  const float* __restrict__ Ag = Aall + ((size_t)bm << 14);
  float* __restrict__ Bg = Ball + ((size_t)bm << 14);
  __shared__ unsigned short dT[2][4096];
  __shared__ float tsh[2];
  int tid = threadIdx.x;
  int w = tid >> 6, lane = tid & 63;
  int ln = lane & 15, q = lane >> 4;

  // trace partials (identical order to the old afrag reduction)
  if (w < 2) {
    float tv = Ag[(size_t)(w * 64 + lane) * 129];
#pragma unroll
    for (int off = 32; off; off >>= 1) tv += __shfl_down(tv, off);
    if (lane == 0) tsh[w] = tv;
  }

  // A-frags from f32 via cvtpk (hi RNE == f2bf; lo = rne(a - hi))
  short8 afr[2][4][2];
#pragma unroll
  for (int mt = 0; mt < 2; ++mt)
#pragma unroll
    for (int kt = 0; kt < 4; ++kt) {
      int m = w * 32 + mt * 16 + ln;
      int k = kt * 32 + q * 8;
      const float* ap = Ag + (size_t)m * 128 + k;
      float4 va = *(const float4*)(ap);
      float4 vb = *(const float4*)(ap + 4);
      float av[8] = {va.x, va.y, va.z, va.w, vb.x, vb.y, vb.z, vb.w};
      uint4 hv, lv;
      unsigned int* hp = (unsigned int*)&hv;
      unsigned int* lp = (unsigned int*)&lv;
#pragma unroll
      for (int jj = 0; jj < 4; ++jj) {
        float a0 = av[2 * jj], a1 = av[2 * jj + 1];
        unsigned int ph = cvtpk(a0, a1);
        float h0 = __uint_as_float(ph << 16);
        float h1 = __uint_as_float(ph & 0xffff0000u);
        unsigned int pl2 = cvtpk(a0 - h0, a1 - h1);
        hp[jj] = ph;
        lp[jj] = pl2;
      }
      afr[mt][kt][0] = *(short8*)&hv;
      afr[mt][kt][1] = *(short8*)&lv;
    }
  __syncthreads();
  float lmax = tsh[0] + tsh[1];

  const float lmin = 0.02f;
  float theta = 0.5f * (lmax + lmin);
  float delta = 0.5f * (lmax - lmin);
  float sigma1 = theta / delta;
  float rho = delta / theta;
  float invtheta = 1.f / theta;

  int wrB[2];
#pragma unroll
  for (int mt = 0; mt < 2; ++mt)
    wrB[mt] = w * 512 + (((mt * 2 + (q >> 1)) & 3) * 16 + ln) * 8 +
              ((q & 1) << 2);

  float xx[2][2][4], rr[2][2][4], dd[2][2][4];  // [nt][mt][rg]
#pragma unroll
  for (int nt = 0; nt < 2; ++nt)
#pragma unroll
    for (int mt = 0; mt < 2; ++mt) {
#pragma unroll
      for (int rg = 0; rg < 4; ++rg) {
        float b = Bg[(w * 32 + mt * 16 + q * 4 + rg) * 128 +
                     cb * 32 + nt * 16 + ln];
        rr[nt][mt][rg] = b;
        xx[nt][mt][rg] = 0.f;
        dd[nt][mt][rg] = b * invtheta;
      }
      unsigned int p01 = cvtpk(dd[nt][mt][0], dd[nt][mt][1]);
      unsigned int p23 = cvtpk(dd[nt][mt][2], dd[nt][mt][3]);
      dd[nt][mt][0] = __uint_as_float(p01 << 16);
      dd[nt][mt][1] = __uint_as_float(p01 & 0xffff0000u);
      dd[nt][mt][2] = __uint_as_float(p23 << 16);
      dd[nt][mt][3] = __uint_as_float(p23 & 0xffff0000u);
      uint2 pk2; pk2.x = p01; pk2.y = p23;
      *(uint2*)(&dT[0][nt * 2048 + wrB[mt]]) = pk2;
    }
  __syncthreads();

#pragma unroll 1
  for (int it = 0; it < 30; ++it) {
    const unsigned short* dTr = dT[it & 1];
    unsigned short* dTw = dT[(it & 1) ^ 1];
    floatx4 acc00 = (floatx4)(0.f), acc01 = (floatx4)(0.f);
    floatx4 acc10 = (floatx4)(0.f), acc11 = (floatx4)(0.f);
#pragma unroll
    for (int kt = 0; kt < 4; ++kt) {
      short8 df0 = *(const short8*)(dTr + kt * 512 + lane * 8);
      short8 df1 = *(const short8*)(dTr + 2048 + kt * 512 + lane * 8);
      acc00 = __builtin_amdgcn_mfma_f32_16x16x32_bf16(afr[0][kt][0], df0, acc00, 0, 0, 0);
      acc00 = __builtin_amdgcn_mfma_f32_16x16x32_bf16(afr[0][kt][1], df0, acc00, 0, 0, 0);
      acc01 = __builtin_amdgcn_mfma_f32_16x16x32_bf16(afr[1][kt][0], df0, acc01, 0, 0, 0);
      acc01 = __builtin_amdgcn_mfma_f32_16x16x32_bf16(afr[1][kt][1], df0, acc01, 0, 0, 0);
      acc10 = __builtin_amdgcn_mfma_f32_16x16x32_bf16(afr[0][kt][0], df1, acc10, 0, 0, 0);
      acc10 = __builtin_amdgcn_mfma_f32_16x16x32_bf16(afr[0][kt][1], df1, acc10, 0, 0, 0);
      acc11 = __builtin_amdgcn_mfma_f32_16x16x32_bf16(afr[1][kt][0], df1, acc11, 0, 0, 0);
      acc11 = __builtin_amdgcn_mfma_f32_16x16x32_bf16(afr[1][kt][1], df1, acc11, 0, 0, 0);
    }
    float rho_n = 1.f / (2.f * sigma1 - rho);
    float c1s = rho_n * rho;
    float c2s = 2.f * rho_n / delta;
#pragma unroll
    for (int nt = 0; nt < 2; ++nt)
#pragma unroll
      for (int mt = 0; mt < 2; ++mt) {
        floatx4 av4 = (nt == 0) ? (mt == 0 ? acc00 : acc01)
                                : (mt == 0 ? acc10 : acc11);
        float dn[4];
#pragma unroll
        for (int rg = 0; rg < 4; ++rg) {
          xx[nt][mt][rg] += dd[nt][mt][rg];
          rr[nt][mt][rg] -= av4[rg];
          dn[rg] = fmaf(c1s, dd[nt][mt][rg], c2s * rr[nt][mt][rg]);
        }
        unsigned int p01 = cvtpk(dn[0], dn[1]);
        unsigned int p23 = cvtpk(dn[2], dn[3]);
        dd[nt][mt][0] = __uint_as_float(p01 << 16);
        dd[nt][mt][1] = __uint_as_float(p01 & 0xffff0000u);
        dd[nt][mt][2] = __uint_as_float(p23 << 16);
        dd[nt][mt][3] = __uint_as_float(p23 & 0xffff0000u);
        uint2 pk2; pk2.x = p01; pk2.y = p23;
        *(uint2*)(&dTw[nt * 2048 + wrB[mt]]) = pk2;
      }
    rho = rho_n;
    __syncthreads();
  }

  // X -> hi/lo bf16 B-operand fragments, in place over this block's own
  // B0 byte-set: hi rows 0..63, lo rows 64..127 (= +16384 shorts).
  unsigned short* Xf = (unsigned short*)Bg;
#pragma unroll
  for (int nt = 0; nt < 2; ++nt)
#pragma unroll
    for (int mt = 0; mt < 2; ++mt) {
      ushort4 h4, l4;
      unsigned short* hp = (unsigned short*)&h4;
      unsigned short* lp = (unsigned short*)&l4;
#pragma unroll
      for (int rg = 0; rg < 4; ++rg) {
        float xv = xx[nt][mt][rg];
        unsigned short h = f2bf(xv);
        hp[rg] = h;
        lp[rg] = f2bf(xv - bf2f(h));
      }
      int l = nt * 2048 + wrB[mt];
      int idx = ((l >> 6) << 8) + (cb << 6) + (l & 63);
      *(ushort4*)(Xf + idx) = h4;
      *(ushort4*)(Xf + idx + 16384) = l4;
    }
}

// ---------------------------------------------------------------------------
// Attention per (h,n), all-MFMA (blocks 0..255) + tcast(Wo) bn<16
// (blocks 256..511).  X read through the 4-way chunk layout from cheb.
// ---------------------------------------------------------------------------
__global__ __launch_bounds__(256) void attn_kernel(
    const unsigned short* __restrict__ q16, const unsigned short* __restrict__ k16,
    const unsigned short* __restrict__ vT16, const unsigned short* __restrict__ Xf,
    const float* __restrict__ vs, const float* __restrict__ cs,
    const float* __restrict__ beta, const float* __restrict__ alpha,
    float* __restrict__ o, const float* __restrict__ Wo,
    unsigned short* __restrict__ WtWo) {
  __shared__ __align__(16) float smem[11264];   // 45056 B union
  int tid = threadIdx.x;

  if (blockIdx.x >= 256) {
    int r = blockIdx.x - 256;        // 0..255
    int bn = r & 15, bk = r >> 4;    // bn in [0,16), bk in [0,16)
    tcast_fat(Wo, WtWo, 2048, 2048, bn, bk, tid, smem);
    return;
  }

  int bid = blockIdx.x;             // h*16+n
  int h = bid >> 4, n = bid & 15;
  int hk = h >> 1;
  unsigned short* qb = (unsigned short*)smem;          // 64*136
  unsigned short* kb = qb + 8704;                      // 64*136
  unsigned short* Sb = kb + 8704;                      // 64*72
  float* csL = smem + 11008;
  float* ecsL = csL + 64;
  float* betaL = ecsL + 64;
  float* alphaL = betaL + 64;
  int w = tid >> 6, lane = tid & 63;
  int ln = lane & 15, hi = lane >> 4;

  {
    size_t qgb = (((size_t)(n * 64)) * 16 + h) * 128;
    size_t kgb = (((size_t)(n * 64)) * 8 + hk) * 128;
#pragma unroll
    for (int g = 0; g < 4; ++g) {
      int i = tid + g * 256;
      int c = i >> 4, ch = i & 15;
      *(uint4*)(qb + c * 136 + ch * 8) =
          *(const uint4*)(q16 + qgb + (size_t)c * 2048 + ch * 8);
      *(uint4*)(kb + c * 136 + ch * 8) =
          *(const uint4*)(k16 + kgb + (size_t)c * 1024 + ch * 8);
    }
    if (tid < 64) {
      float cv = cs[bid * 64 + tid];
      csL[tid] = cv;
      ecsL[tid] = expf(cv);
      betaL[tid] = beta[(n * 64 + tid) * 16 + h];
      alphaL[tid] = alpha[(n * 64 + tid) * 16 + h];
    }
  }
  __syncthreads();

  short8 aq[4];
#pragma unroll
  for (int dt = 0; dt < 4; ++dt)
    aq[dt] = *(const short8*)(qb + (w * 16 + ln) * 136 + dt * 32 + hi * 8);

  // phase 1: o_inter = q @ X (hi+lo planes), then scale rows by exp(cs)
  const unsigned short* Xb = Xf + ((size_t)bid << 15);
  floatx4 acc[8];
#pragma unroll
  for (int et = 0; et < 8; ++et) {
    int ntl = et & 1, cbq = et >> 1;
    floatx4 a = (floatx4)(0.f);
#pragma unroll
    for (int dt = 0; dt < 4; ++dt) {
      int l = ntl * 2048 + dt * 512 + lane * 8;
      int base = ((l >> 6) << 8) + (cbq << 6) + (l & 63);
      short8 xh = *(const short8*)(Xb + base);
      short8 xl = *(const short8*)(Xb + base + 16384);
      a = __builtin_amdgcn_mfma_f32_16x16x32_bf16(aq[dt], xh, a, 0, 0, 0);
      a = __builtin_amdgcn_mfma_f32_16x16x32_bf16(aq[dt], xl, a, 0, 0, 0);
    }
    acc[et] = a;
  }
#pragma unroll
  for (int et = 0; et < 8; ++et)
#pragma unroll
    for (int rg = 0; rg < 4; ++rg)
      acc[et][rg] *= ecsL[w * 16 + hi * 4 + rg];

  // phase 2: gated causal scores -> Sb (bf16), wave-local rows
#pragma unroll
  for (int jt = 0; jt < 4; ++jt) {
    if (jt <= w) {
      floatx4 s = (floatx4)(0.f);
#pragma unroll
      for (int dt = 0; dt < 4; ++dt) {
        short8 bk = *(const short8*)(kb + (jt * 16 + ln) * 136 + dt * 32 + hi * 8);
        s = __builtin_amdgcn_mfma_f32_16x16x32_bf16(aq[dt], bk, s, 0, 0, 0);
      }
      int j = jt * 16 + ln;
      float csj = csL[j], bj = betaL[j];
#pragma unroll
      for (int rg = 0; rg < 4; ++rg) {
        int c = w * 16 + hi * 4 + rg;
        float v = (j <= c) ? s[rg] * expf(csL[c] - csj) * bj : 0.f;
        Sb[c * 72 + j] = f2bf(v);
      }
    } else {
#pragma unroll
      for (int rg = 0; rg < 4; ++rg)
        Sb[(w * 16 + hi * 4 + rg) * 72 + jt * 16 + ln] = 0;
    }
  }

  // phase 3: O += S @ v
  const unsigned short* vTb = vT16 + ((size_t)(n * 8 + hk) << 13);
#pragma unroll
  for (int et = 0; et < 8; ++et) {
#pragma unroll
    for (int kt = 0; kt < 2; ++kt) {
      short8 as = *(const short8*)(Sb + (w * 16 + ln) * 72 + kt * 32 + hi * 8);
      short8 bv = *(const short8*)(vTb + (et * 16 + ln) * 64 + kt * 32 + hi * 8);
      acc[et] = __builtin_amdgcn_mfma_f32_16x16x32_bf16(as, bv, acc[et], 0, 0, 0);
    }
  }

  // epilogue: + alpha*v, store
#pragma unroll
  for (int et = 0; et < 8; ++et) {
#pragma unroll
    for (int rg = 0; rg < 4; ++rg) {
      int c = w * 16 + hi * 4 + rg, e = et * 16 + ln;
      size_t oaddr = (((size_t)(n * 64 + c)) * 16 + h) * 128 + e;
      size_t vaddr = (((size_t)(n * 64 + c)) * 8 + hk) * 128 + e;
      o[oaddr] = acc[et][rg] + alphaL[c] * vs[vaddr];
    }
  }
}

// ---------------------------------------------------------------------------
// rmso: tcast(Wo) bn>=16 (blocks 0..255) + gated RMSNorm (256..4351).
// ---------------------------------------------------------------------------
__global__ __launch_bounds__(256) void rmso_kernel(
    const float* __restrict__ o, const float* __restrict__ xall,
    const float* __restrict__ norm_w, unsigned short* __restrict__ onorm,
    const float* __restrict__ Wo, unsigned short* __restrict__ WtWo) {
  __shared__ float t[128 * 65];
  int b = blockIdx.x, tid = threadIdx.x;
  if (b < 256) {
    int bn = 16 + (b & 15), bk = b >> 4;   // bn in [16,32), bk in [0,16)
    tcast_fat(Wo, WtWo, 2048, 2048, bn, bk, tid, t);
  } else {
    int bb = b - 256;
    int wave = tid >> 6, lane = tid & 63;
    int row = bb * 4 + wave;         // t*16 + h
    size_t base = (size_t)row * HDIM;
    size_t gbase = (size_t)(row >> 4) * 6144 + 4096 + (size_t)(row & 15) * HDIM;
    float v0 = o[base + lane], v1 = o[base + lane + 64];
    float ss = fmaf(v0, v0, v1 * v1);
#pragma unroll
    for (int off = 32; off; off >>= 1) ss += __shfl_down(ss, off);
    ss = __shfl(ss, 0);
    float rinv = rsqrtf(ss * (1.f / 128.f) + 1e-6f);
    float g0 = xall[gbase + lane], g1 = xall[gbase + lane + 64];
    float s0 = g0 / (1.f + expf(-g0));
    float s1 = g1 / (1.f + expf(-g1));
    onorm[base + lane]      = f2bf(v0 * rinv * norm_w[lane] * s0);
    onorm[base + lane + 64] = f2bf(v1 * rinv * norm_w[lane + 64] * s1);
  }
}

// ---------------------------------------------------------------------------
extern "C" void kernel_launch(void* const* d_in, const int* in_sizes, int n_in,
                              void* d_out, int out_size, void* d_ws,
                              size_t ws_size, hipStream_t stream) {
  (void)in_sizes; (void)n_in; (void)out_size; (void)ws_size;
  const float* x      = (const float*)d_in[0];
  const float* Wq     = (const float*)d_in[1];
  const float* Wk     = (const float*)d_in[2];
  const float* Wv     = (const float*)d_in[3];
  const float* convq  = (const float*)d_in[4];
  const float* convk  = (const float*)d_in[5];
  const float* convv  = (const float*)d_in[6];
  const float* Wa     = (const float*)d_in[7];
  const float* A_log  = (const float*)d_in[8];
  const float* dtb    = (const float*)d_in[9];
  const float* Wb     = (const float*)d_in[10];
  const float* bbv    = (const float*)d_in[11];
  const float* Wal    = (const float*)d_in[12];
  const float* balv   = (const float*)d_in[13];
  const float* Wg     = (const float*)d_in[14];
  const float* norm_w = (const float*)d_in[15];
  const float* Wo     = (const float*)d_in[16];
  float* out = (float*)d_out;

  // workspace layout (float slots), ~88.5 MB total
  float* p = (float*)d_ws;
  float* xall  = p; p += 6291456;   // [L][6144]: q|k|v|g projections
  float* qslot = p; p += 2097152;   // carved: qs16 | ks16 | vT16 (bf16)
  float* ks2   = p; p += 1048576;   // + vs2: reused as WtWo (bf16) post-attn
  float* vs2   = p; p += 1048576;
  float* ob    = p; p += 2097152;
  float* glog  = p; p += 16384;
  float* beta  = p; p += 16384;
  float* alpha = p; p += 16384;
  float* csb   = p; p += 16384;
  float* wend  = p; p += 16384;
  float* traces= p; p += 16384;     // unused (trace folded into cheb)
  float* dHn   = p; p += 4194304;   // -> A (f32, read directly by cheb)
  float* dBn   = p; p += 4194304;   // -> B0 -> X-frags (bf16 hi/lo) in place
  unsigned short* xb16 = (unsigned short*)p; p += 1048576;
  (void)traces;

  unsigned short* qs16 = (unsigned short*)qslot;     // 1024*2048
  unsigned short* ks16 = qs16 + 2097152;             // 1024*1024
  unsigned short* vT16 = ks16 + 1048576;             // 128*128*64
  unsigned short* WtAll = (unsigned short*)dHn;      // 24 MB over dHn+dBn
  unsigned short* WtWo  = (unsigned short*)ks2;      // 8 MB over ks2+vs2
  unsigned short* onorm16 = xb16;                    // free after projections

  dim3 blk(256);
  // gates (wave per (t,g), coalesced) + fat tcast q|k|v|g + castbf(x)
  prep_kernel<<<2816, blk, 0, stream>>>(x, Wq, Wk, Wv, Wg, xb16, WtAll,
                                        Wa, Wb, Wal, A_log, dtb, bbv, balv,
                                        glog, beta, alpha);
  gemm_lds<128, 64><<<dim3(96, 8), blk, 0, stream>>>(xb16, WtAll, xall,
                                                     1024, 6144, 2048);
  // causal conv + silu (q scaled by HD^-0.5) + cumsum/w_end tail block
  conv_all<<<16385, blk, 0, stream>>>(xall, convq, convk, convv,
                                      qs16, ks2, ks16, vs2,
                                      glog, beta, csb, wend);
  // gram increments (MFMA) + v-transpose blocks, scan, Chebyshev (4-way
  // split, in-prologue cvtpk A-frag conversion + trace)
  dhb_kernel<<<384, blk, 0, stream>>>(ks2, vs2, wend, dHn, dBn, vT16);
  scan_kernel<<<1024, blk, 0, stream>>>(dHn, dBn, csb);
  cheb_kernel<<<1024, blk, 0, stream>>>(dHn, dBn);
  // attention (all-MFMA) + tcast(Wo) rows < 1024 (ks2 region, dead)
  attn_kernel<<<512, blk, 0, stream>>>(qs16, ks16, vT16, (unsigned short*)dBn,
                                       vs2, csb, beta, alpha, ob, Wo, WtWo);
  // tcast(Wo) rows >= 1024 (vs2 region, dead after attn) + RMSNorm
  rmso_kernel<<<4352, blk, 0, stream>>>(ob, xall, norm_w, onorm16, Wo, WtWo);
  gemm_lds<64, 64><<<dim3(32, 16), blk, 0, stream>>>(onorm16, WtWo, out,
                                                     1024, 2048, 2048);
}